// Round 9
// baseline (990.083 us; speedup 1.0000x reference)
//
#include <hip/hip_runtime.h>
#include <math.h>

constexpr int Bn = 8, NZ = 16, Ln = 512;
constexpr int E = 256, DM = 512, NH = 16, HD = 32;
constexpr int FF = 1024, NL = 8, E1D = 32, PDIM = 64, PMAX = 24;
constexpr int ROWS = Bn * Ln;                       // 4096
constexpr float QSCALE = 0.04419417382415922f;      // 1/sqrt(512)

typedef __attribute__((ext_vector_type(8))) short bf16x8;
typedef __attribute__((ext_vector_type(4))) float floatx4;

__device__ inline unsigned short f2b(float f) {
  union { float f; unsigned u; } v; v.f = f;
  unsigned r = (v.u + 0x7FFF + ((v.u >> 16) & 1)) >> 16;
  return (unsigned short)r;
}
__device__ inline float b2f(unsigned short u) {
  union { unsigned u; float f; } v; v.u = ((unsigned)u) << 16; return v.f;
}

// ---------------------------------------------------------------------------
// batched Wq/Wk/Wv fp32 [l][E][DM] -> bf16 qkvT [l][3*DM][E]
// ---------------------------------------------------------------------------
__global__ __launch_bounds__(256) void transpose_qkv(
    const float* __restrict__ Wq, const float* __restrict__ Wk,
    const float* __restrict__ Wv, unsigned short* __restrict__ qkvT)
{
  __shared__ float t[32][33];
  int zb = blockIdx.z;
  int which = zb / NL, l = zb % NL;
  const float* s = (which == 0 ? Wq : which == 1 ? Wk : Wv) + (size_t)l * E * DM;
  unsigned short* d = qkvT + (size_t)l * 3 * DM * E + (size_t)which * DM * E;
  int c0 = blockIdx.x * 32, r0 = blockIdx.y * 32;
  int tx = threadIdx.x & 31, ty = threadIdx.x >> 5;
  #pragma unroll
  for (int i = 0; i < 4; ++i)
    t[ty + i * 8][tx] = s[(size_t)(r0 + ty + i * 8) * DM + c0 + tx];
  __syncthreads();
  #pragma unroll
  for (int i = 0; i < 4; ++i)
    d[(size_t)(c0 + ty + i * 8) * E + r0 + tx] = f2b(t[tx][ty + i * 8]);
}

// ---------------------------------------------------------------------------
// generic fp32 [l][R][C] -> bf16 [l][C][R]
// ---------------------------------------------------------------------------
__global__ __launch_bounds__(256) void transpose_bf16(
    const float* __restrict__ src, unsigned short* __restrict__ dst,
    int R, int C, size_t sls, size_t dls)
{
  __shared__ float t[32][33];
  int l = blockIdx.z;
  int c0 = blockIdx.x * 32, r0 = blockIdx.y * 32;
  int tx = threadIdx.x & 31, ty = threadIdx.x >> 5;
  const float* s = src + (size_t)l * sls;
  unsigned short* d = dst + (size_t)l * dls;
  #pragma unroll
  for (int i = 0; i < 4; ++i)
    t[ty + i * 8][tx] = s[(size_t)(r0 + ty + i * 8) * C + c0 + tx];
  __syncthreads();
  #pragma unroll
  for (int i = 0; i < 4; ++i)
    d[(size_t)(c0 + ty + i * 8) * R + r0 + tx] = f2b(t[tx][ty + i * 8]);
}

// ---------------------------------------------------------------------------
// embed stage 1: t0 = relu(z^T @ ex_w1 + b1) fp32; e_aa gather into umb
// ---------------------------------------------------------------------------
__global__ __launch_bounds__(256) void embed1_kernel(
    const float* __restrict__ z, const float* __restrict__ x,
    const float* __restrict__ aa,
    const float* __restrict__ w1, const float* __restrict__ b1,
    float* __restrict__ t0, unsigned short* __restrict__ umb)
{
  int row = blockIdx.x;
  int b = row >> 9, l = row & (Ln - 1);
  int t = threadIdx.x;
  __shared__ float zs[NZ];
  __shared__ int am_s;
  if (t < NZ) zs[t] = z[((size_t)b * NZ + t) * Ln + l];
  if (t == 0) {
    const float* xp = x + (size_t)b * 20 * Ln + l;
    int am = 0; float bv = xp[0];
    for (int c = 1; c < 20; ++c) { float vv = xp[(size_t)c * Ln]; if (vv > bv) { bv = vv; am = c; } }
    am_s = am;
  }
  __syncthreads();
  float a1 = b1[t];
  #pragma unroll
  for (int nz = 0; nz < NZ; ++nz) a1 += zs[nz] * w1[nz * E + t];
  t0[(size_t)row * E + t] = fmaxf(a1, 0.f);
  if (t < E1D) umb[(size_t)row * (E + E1D) + E + t] = f2b(aa[am_s * E1D + t]);
}

// ---------------------------------------------------------------------------
// pairwise-bias collapse: 49 bins per (layer, head)
// ---------------------------------------------------------------------------
__global__ __launch_bounds__(256) void bias_kernel(
    const float* __restrict__ pos, const float* __restrict__ W2d,
    const float* __restrict__ b2d, float* __restrict__ bias49)
{
  int layer = blockIdx.x;
  for (int idx = threadIdx.x; idx < NH * 49; idx += 256) {
    int hh = idx / 49, bin = idx % 49;
    float acc = b2d[layer * NH + hh];
    for (int p = 0; p < PDIM; ++p)
      acc += pos[bin * PDIM + p] * W2d[((size_t)layer * PDIM + p) * NH + hh];
    bias49[(size_t)layer * NH * 49 + hh * 49 + bin] = acc;
  }
}

// ---------------------------------------------------------------------------
// bf16 MFMA GEMM, BK=32 + register prefetch: C = act(A @ Bt^T * scale + bias)
// Instantiated 64x128 (768/512-block grids, 3-4 blocks/CU) for QKV and FF1.
// Ascending-k accumulation — output bitwise identical to prior rounds.
// ---------------------------------------------------------------------------
template<int BM, int BN, bool BIAS, bool RELU, bool OUTBF16, bool QKV>
__global__ __launch_bounds__(256) void gemm_mfma(
    const unsigned short* __restrict__ A, const unsigned short* __restrict__ Bt,
    const float* __restrict__ bias,
    float* __restrict__ Cf, unsigned short* __restrict__ Cb, int N, int K)
{
  constexpr int MT = BM / 32, NT = BN / 32;
  constexpr int AIT = BM / 64, BIT = BN / 64;
  __shared__ __align__(16) unsigned short As[BM][40];
  __shared__ __align__(16) unsigned short Bs[BN][40];
  const int tid = threadIdx.x;
  const int wave = tid >> 6, ln = tid & 63;
  const int quad = ln >> 4, l16 = ln & 15;
  const int wm = wave >> 1, wn = wave & 1;
  const int m0 = blockIdx.y * BM, n0 = blockIdx.x * BN;

  floatx4 acc[MT][NT] = {};

  float4 pa[AIT], pb[BIT];
  #pragma unroll
  for (int it = 0; it < AIT; ++it) {
    int c = tid + it * 256; int row = c >> 2, cc = (c & 3) * 8;
    pa[it] = *(const float4*)(A + (size_t)(m0 + row) * K + cc);
  }
  #pragma unroll
  for (int it = 0; it < BIT; ++it) {
    int c = tid + it * 256; int row = c >> 2, cc = (c & 3) * 8;
    pb[it] = *(const float4*)(Bt + (size_t)(n0 + row) * K + cc);
  }

  for (int kb = 0; kb < K; kb += 32) {
    __syncthreads();
    #pragma unroll
    for (int it = 0; it < AIT; ++it) {
      int c = tid + it * 256; int row = c >> 2, cc = (c & 3) * 8;
      *(float4*)&As[row][cc] = pa[it];
    }
    #pragma unroll
    for (int it = 0; it < BIT; ++it) {
      int c = tid + it * 256; int row = c >> 2, cc = (c & 3) * 8;
      *(float4*)&Bs[row][cc] = pb[it];
    }
    if (kb + 32 < K) {
      #pragma unroll
      for (int it = 0; it < AIT; ++it) {
        int c = tid + it * 256; int row = c >> 2, cc = (c & 3) * 8;
        pa[it] = *(const float4*)(A + (size_t)(m0 + row) * K + kb + 32 + cc);
      }
      #pragma unroll
      for (int it = 0; it < BIT; ++it) {
        int c = tid + it * 256; int row = c >> 2, cc = (c & 3) * 8;
        pb[it] = *(const float4*)(Bt + (size_t)(n0 + row) * K + kb + 32 + cc);
      }
    }
    __syncthreads();
    bf16x8 af[MT], bfr[NT];
    #pragma unroll
    for (int i = 0; i < MT; ++i)
      af[i] = *(const bf16x8*)&As[wm * (BM / 2) + i * 16 + l16][quad * 8];
    #pragma unroll
    for (int j = 0; j < NT; ++j)
      bfr[j] = *(const bf16x8*)&Bs[wn * (BN / 2) + j * 16 + l16][quad * 8];
    #pragma unroll
    for (int i = 0; i < MT; ++i)
      #pragma unroll
      for (int j = 0; j < NT; ++j)
        acc[i][j] = __builtin_amdgcn_mfma_f32_16x16x32_bf16(af[i], bfr[j], acc[i][j], 0, 0, 0);
  }

  #pragma unroll
  for (int i = 0; i < MT; ++i)
    #pragma unroll
    for (int j = 0; j < NT; ++j) {
      int col = n0 + wn * (BN / 2) + j * 16 + l16;
      float bv = BIAS ? bias[col] : 0.f;
      float sc = QKV ? (col < 512 ? QSCALE : 1.f) : 1.f;
      #pragma unroll
      for (int r = 0; r < 4; ++r) {
        int rowg = m0 + wm * (BM / 2) + i * 16 + quad * 4 + r;
        float v = acc[i][j][r] * sc + bv;
        if (RELU) v = fmaxf(v, 0.f);
        if (OUTBF16) Cb[(size_t)rowg * N + col] = f2b(v);
        else Cf[(size_t)rowg * N + col] = v;
      }
    }
}

// ---------------------------------------------------------------------------
// N=256 GEMM: BM=BN=32, BK=64, flat 1024-block grid with XCD-aware swizzle:
// xcd = id&7 owns m-slab [xcd*512, xcd*512+512) for ALL n -> each XCD's L2
// streams a 1MB A-slab once (kills the 8x A-reload through L3).
// Register prefetch on top. Ascending-k order -> bitwise-identical output.
// ---------------------------------------------------------------------------
__global__ __launch_bounds__(256) void gemm_n256(
    const unsigned short* __restrict__ A, const unsigned short* __restrict__ Bt,
    const float* __restrict__ bias, const float* __restrict__ resid,
    float* __restrict__ Cf, int K)
{
  __shared__ __align__(16) unsigned short As[32][72];
  __shared__ __align__(16) unsigned short Bs[32][72];
  const int tid = threadIdx.x;
  const int wave = tid >> 6, ln = tid & 63;
  const int quad = ln >> 4, l16 = ln & 15;
  const int wm = wave >> 1, wn = wave & 1;
  const int id = blockIdx.x;
  const int xcd = id & 7, idx = id >> 3;
  const int m0 = (xcd * 16 + (idx & 15)) * 32;   // m-slab local to this XCD
  const int n0 = (idx >> 4) * 32;
  const int srow = tid >> 3, scol = (tid & 7) * 8;

  floatx4 acc = {};
  float4 ta = *(const float4*)(A + (size_t)(m0 + srow) * K + scol);
  float4 tb = *(const float4*)(Bt + (size_t)(n0 + srow) * K + scol);

  for (int kb = 0; kb < K; kb += 64) {
    __syncthreads();
    *(float4*)&As[srow][scol] = ta;
    *(float4*)&Bs[srow][scol] = tb;
    if (kb + 64 < K) {
      ta = *(const float4*)(A + (size_t)(m0 + srow) * K + kb + 64 + scol);
      tb = *(const float4*)(Bt + (size_t)(n0 + srow) * K + kb + 64 + scol);
    }
    __syncthreads();
    #pragma unroll
    for (int kc = 0; kc < 2; ++kc) {
      bf16x8 af = *(const bf16x8*)&As[wm * 16 + l16][kc * 32 + quad * 8];
      bf16x8 bf = *(const bf16x8*)&Bs[wn * 16 + l16][kc * 32 + quad * 8];
      acc = __builtin_amdgcn_mfma_f32_16x16x32_bf16(af, bf, acc, 0, 0, 0);
    }
  }

  const int col = n0 + wn * 16 + l16;
  const float bv = bias[col];
  #pragma unroll
  for (int r = 0; r < 4; ++r) {
    int rowg = m0 + wm * 16 + quad * 4 + r;
    Cf[(size_t)rowg * 256 + col] = acc[r] + bv + resid[(size_t)rowg * 256 + col];
  }
}

// ---------------------------------------------------------------------------
// MFMA flash attention (unchanged — verified)
// ---------------------------------------------------------------------------
__global__ __launch_bounds__(256) void attn_kernel(
    const unsigned short* __restrict__ qkv, const float* __restrict__ bias49,
    unsigned short* __restrict__ o)
{
  const int i0 = blockIdx.x * 64;
  const int bh = blockIdx.y;
  const int b = bh >> 4, hh = bh & 15;
  const int tid = threadIdx.x;
  const int wave = tid >> 6, ln = tid & 63;
  const int quad = ln >> 4, l16 = ln & 15;

  __shared__ __align__(16) unsigned short Kt[64][40];
  __shared__ __align__(16) unsigned short Vt[32][72];
  __shared__ __align__(16) unsigned short Pw[4][2][16][72];
  __shared__ float bsh[49];

  if (tid < 49) bsh[tid] = bias49[hh * 49 + tid];

  const unsigned short* qkvb = qkv + (size_t)b * Ln * 1536;

  const int qrow = i0 + wave * 16 + l16;
  const bf16x8 qf = *(const bf16x8*)(qkvb + (size_t)qrow * 1536 + hh * 32 + quad * 8);

  float m[4], l[4];
  #pragma unroll
  for (int r = 0; r < 4; ++r) { m[r] = -1e30f; l[r] = 0.f; }
  floatx4 acc_o[2] = {};

  const int krow = tid >> 2, kch = (tid & 3) * 8;
  const int vkey = tid & 63, vch = (tid >> 6) * 8;

  for (int jt = 0; jt < 8; ++jt) {
    const int j0 = jt * 64;
    __syncthreads();
    *(float4*)&Kt[krow][kch] =
        *(const float4*)(qkvb + (size_t)(j0 + krow) * 1536 + 512 + hh * 32 + kch);
    bf16x8 vv = *(const bf16x8*)(qkvb + (size_t)(j0 + vkey) * 1536 + 1024 + hh * 32 + vch);
    #pragma unroll
    for (int i = 0; i < 8; ++i) Vt[vch + i][vkey] = (unsigned short)vv[i];
    __syncthreads();

    floatx4 s4[4];
    #pragma unroll
    for (int t = 0; t < 4; ++t) {
      bf16x8 kf = *(const bf16x8*)&Kt[16 * t + l16][quad * 8];
      s4[t] = __builtin_amdgcn_mfma_f32_16x16x32_bf16(qf, kf, (floatx4){0.f, 0.f, 0.f, 0.f}, 0, 0, 0);
    }
    const int relmin = j0 - (i0 + 63), relmax = j0 + 63 - i0;
    if (relmin >= PMAX) {
      float bc = bsh[48];
      #pragma unroll
      for (int t = 0; t < 4; ++t)
        #pragma unroll
        for (int r = 0; r < 4; ++r) s4[t][r] += bc;
    } else if (relmax <= -PMAX) {
      float bc = bsh[0];
      #pragma unroll
      for (int t = 0; t < 4; ++t)
        #pragma unroll
        for (int r = 0; r < 4; ++r) s4[t][r] += bc;
    } else {
      const int base_rel = (j0 + l16) - (i0 + wave * 16 + quad * 4);
      #pragma unroll
      for (int t = 0; t < 4; ++t)
        #pragma unroll
        for (int r = 0; r < 4; ++r) {
          int rel = base_rel + 16 * t - r;
          rel = rel < -PMAX ? -PMAX : (rel > PMAX ? PMAX : rel);
          s4[t][r] += bsh[rel + PMAX];
        }
    }

    float mloc[4], alpha[4], psum[4];
    #pragma unroll
    for (int r = 0; r < 4; ++r) {
      mloc[r] = fmaxf(fmaxf(s4[0][r], s4[1][r]), fmaxf(s4[2][r], s4[3][r]));
      #pragma unroll
      for (int off = 1; off < 16; off <<= 1)
        mloc[r] = fmaxf(mloc[r], __shfl_xor(mloc[r], off, 64));
      float mnew = fmaxf(m[r], mloc[r]);
      alpha[r] = __expf(m[r] - mnew);
      m[r] = mnew;
      psum[r] = 0.f;
    }
    #pragma unroll
    for (int t = 0; t < 4; ++t)
      #pragma unroll
      for (int r = 0; r < 4; ++r) {
        float p = __expf(s4[t][r] - m[r]);
        s4[t][r] = p;
        psum[r] += p;
      }
    #pragma unroll
    for (int r = 0; r < 4; ++r) {
      #pragma unroll
      for (int off = 1; off < 16; off <<= 1)
        psum[r] += __shfl_xor(psum[r], off, 64);
      l[r] = l[r] * alpha[r] + psum[r];
      acc_o[0][r] *= alpha[r];
      acc_o[1][r] *= alpha[r];
    }

    #pragma unroll
    for (int t = 0; t < 4; ++t)
      #pragma unroll
      for (int r = 0; r < 4; ++r) {
        float p = s4[t][r];
        unsigned short hi = f2b(p);
        unsigned short lo = f2b(p - b2f(hi));
        Pw[wave][0][quad * 4 + r][16 * t + l16] = hi;
        Pw[wave][1][quad * 4 + r][16 * t + l16] = lo;
      }

    #pragma unroll
    for (int kh = 0; kh < 2; ++kh) {
      bf16x8 phi = *(const bf16x8*)&Pw[wave][0][l16][kh * 32 + quad * 8];
      bf16x8 plo = *(const bf16x8*)&Pw[wave][1][l16][kh * 32 + quad * 8];
      #pragma unroll
      for (int nt = 0; nt < 2; ++nt) {
        bf16x8 vf = *(const bf16x8*)&Vt[nt * 16 + l16][kh * 32 + quad * 8];
        acc_o[nt] = __builtin_amdgcn_mfma_f32_16x16x32_bf16(phi, vf, acc_o[nt], 0, 0, 0);
        acc_o[nt] = __builtin_amdgcn_mfma_f32_16x16x32_bf16(plo, vf, acc_o[nt], 0, 0, 0);
      }
    }
  }

  #pragma unroll
  for (int r = 0; r < 4; ++r) {
    float inv = 1.f / l[r];
    size_t rowg = (size_t)b * Ln + i0 + wave * 16 + quad * 4 + r;
    #pragma unroll
    for (int nt = 0; nt < 2; ++nt)
      o[rowg * 512 + hh * 32 + nt * 16 + l16] = f2b(acc_o[nt][r] * inv);
  }
}

// ---------------------------------------------------------------------------
// LayerNorm over E=256; writes h (fp32) and a bf16 mirror with given stride
// ---------------------------------------------------------------------------
__global__ __launch_bounds__(256) void ln_kernel(
    const float* __restrict__ xin, const float* __restrict__ g,
    const float* __restrict__ be, float* __restrict__ hout,
    unsigned short* __restrict__ bout, int bstride)
{
  int row = blockIdx.x, t = threadIdx.x;
  float v = xin[(size_t)row * E + t];
  float s = v;
  #pragma unroll
  for (int off = 32; off > 0; off >>= 1) s += __shfl_down(s, off, 64);
  __shared__ float ws4[4];
  __shared__ float mbc, rbc;
  if ((t & 63) == 0) ws4[t >> 6] = s;
  __syncthreads();
  if (t == 0) mbc = (ws4[0] + ws4[1] + ws4[2] + ws4[3]) * (1.f / E);
  __syncthreads();
  float m = mbc;
  float d = v - m;
  float s2 = d * d;
  #pragma unroll
  for (int off = 32; off > 0; off >>= 1) s2 += __shfl_down(s2, off, 64);
  if ((t & 63) == 0) ws4[t >> 6] = s2;
  __syncthreads();
  if (t == 0) rbc = rsqrtf((ws4[0] + ws4[1] + ws4[2] + ws4[3]) * (1.f / E) + 1e-5f);
  __syncthreads();
  float y = d * rbc * g[t] + be[t];
  hout[(size_t)row * E + t] = y;
  bout[(size_t)row * bstride + t] = f2b(y);
}

// ---------------------------------------------------------------------------
// fp32 tiled GEMM: C = act(A@B + bias), optional bf16 mirror (embed2 / head)
// ---------------------------------------------------------------------------
template<bool RELU, bool BIAS, bool MIRROR>
__global__ __launch_bounds__(256) void gemm64f(
    const float* __restrict__ A, const float* __restrict__ B,
    const float* __restrict__ bias, float* __restrict__ C,
    unsigned short* __restrict__ mir, int N, int K)
{
  __shared__ __align__(16) float As[16][64];
  __shared__ __align__(16) float Bss[16][68];
  const int tid = threadIdx.x;
  const int tx = tid & 15, ty = tid >> 4;
  const int m0 = blockIdx.y * 64, n0 = blockIdx.x * 64;
  const int arow = tid >> 2, acol = (tid & 3) * 4;
  const int brow = tid >> 6, bcol = tid & 63;
  float acc[4][4] = {};
  for (int kb = 0; kb < K; kb += 16) {
    __syncthreads();
    float4 av = *(const float4*)(A + (size_t)(m0 + arow) * K + kb + acol);
    As[acol + 0][arow] = av.x; As[acol + 1][arow] = av.y;
    As[acol + 2][arow] = av.z; As[acol + 3][arow] = av.w;
    #pragma unroll
    for (int kk = 0; kk < 4; ++kk)
      Bss[brow + kk * 4][bcol] = B[(size_t)(kb + brow + kk * 4) * N + n0 + bcol];
    __syncthreads();
    #pragma unroll
    for (int k = 0; k < 16; ++k) {
      float4 a = *(const float4*)&As[k][4 * ty];
      float4 b = *(const float4*)&Bss[k][4 * tx];
      float av4[4] = {a.x, a.y, a.z, a.w};
      float bv4[4] = {b.x, b.y, b.z, b.w};
      #pragma unroll
      for (int ii = 0; ii < 4; ++ii)
        #pragma unroll
        for (int jj = 0; jj < 4; ++jj)
          acc[ii][jj] += av4[ii] * bv4[jj];
    }
  }
  #pragma unroll
  for (int ii = 0; ii < 4; ++ii) {
    size_t row = (size_t)m0 + 4 * ty + ii;
    int col = n0 + 4 * tx;
    float4 vv;
    vv.x = acc[ii][0]; vv.y = acc[ii][1]; vv.z = acc[ii][2]; vv.w = acc[ii][3];
    if (BIAS) {
      float4 bb = *(const float4*)(bias + col);
      vv.x += bb.x; vv.y += bb.y; vv.z += bb.z; vv.w += bb.w;
    }
    if (RELU) {
      vv.x = fmaxf(vv.x, 0.f); vv.y = fmaxf(vv.y, 0.f);
      vv.z = fmaxf(vv.z, 0.f); vv.w = fmaxf(vv.w, 0.f);
    }
    *(float4*)(C + row * N + col) = vv;
    if (MIRROR) {
      ushort4 mv;
      mv.x = f2b(vv.x); mv.y = f2b(vv.y); mv.z = f2b(vv.z); mv.w = f2b(vv.w);
      *(ushort4*)(mir + row * N + col) = mv;
    }
  }
}

__global__ __launch_bounds__(256) void final_r_kernel(
    const float* __restrict__ t1, const float* __restrict__ w2,
    const float* __restrict__ b2, float* __restrict__ r)
{
  int row = blockIdx.x, t = threadIdx.x;
  float xv = t1[(size_t)row * E + t];
  float p0 = xv * w2[t * 3 + 0];
  float p1 = xv * w2[t * 3 + 1];
  float p2 = xv * w2[t * 3 + 2];
  #pragma unroll
  for (int off = 32; off > 0; off >>= 1) {
    p0 += __shfl_down(p0, off, 64);
    p1 += __shfl_down(p1, off, 64);
    p2 += __shfl_down(p2, off, 64);
  }
  __shared__ float red[4][3];
  if ((t & 63) == 0) { int w = t >> 6; red[w][0] = p0; red[w][1] = p1; red[w][2] = p2; }
  __syncthreads();
  if (t < 3)
    r[(size_t)row * 3 + t] = red[0][t] + red[1][t] + red[2][t] + red[3][t] + b2[t];
}

__global__ __launch_bounds__(512) void dist_kernel(
    const float* __restrict__ r, float* __restrict__ out)
{
  int bi = blockIdx.x;
  int j = threadIdx.x;
  int b = bi >> 9;
  float x0 = r[(size_t)bi * 3 + 0];
  float y0 = r[(size_t)bi * 3 + 1];
  float z0 = r[(size_t)bi * 3 + 2];
  const float* rj = r + ((size_t)b * Ln + j) * 3;
  float dx = rj[0] - x0, dy = rj[1] - y0, dz = rj[2] - z0;
  out[(size_t)bi * Ln + j] = sqrtf(dx * dx + dy * dy + dz * dz + 1e-12f);
}

// ---------------------------------------------------------------------------
extern "C" void kernel_launch(void* const* d_in, const int* in_sizes, int n_in,
                              void* d_out, int out_size, void* d_ws, size_t ws_size,
                              hipStream_t stream)
{
  const float* z     = (const float*)d_in[0];
  const float* x     = (const float*)d_in[1];
  const float* pos   = (const float*)d_in[2];
  const float* aa    = (const float*)d_in[3];
  const float* ex_w1 = (const float*)d_in[4];
  const float* ex_b1 = (const float*)d_in[5];
  const float* ex_w2 = (const float*)d_in[6];
  const float* ex_b2 = (const float*)d_in[7];
  const float* Wq    = (const float*)d_in[8];
  const float* Wk    = (const float*)d_in[9];
  const float* Wv    = (const float*)d_in[10];
  const float* Wo    = (const float*)d_in[11];
  const float* bo    = (const float*)d_in[12];
  const float* W2d   = (const float*)d_in[13];
  const float* b2d   = (const float*)d_in[14];
  const float* W1    = (const float*)d_in[15];
  const float* b1    = (const float*)d_in[16];
  const float* W2    = (const float*)d_in[17];
  const float* b2    = (const float*)d_in[18];
  const float* g1    = (const float*)d_in[19];
  const float* be1   = (const float*)d_in[20];
  const float* g2    = (const float*)d_in[21];
  const float* be2   = (const float*)d_in[22];
  const float* m3w1  = (const float*)d_in[23];
  const float* m3b1  = (const float*)d_in[24];
  const float* m3w2  = (const float*)d_in[25];
  const float* m3b2  = (const float*)d_in[26];

  float* ws     = (float*)d_ws;
  float* h      = ws;                          // 4096*256
  float* t0     = h + (size_t)ROWS * E;        // 4096*256 (embed hidden / tmp)
  float* r      = t0 + (size_t)ROWS * E;       // 4096*3
  float* bias49 = r + (size_t)ROWS * 3;        // 8*16*49
  unsigned short* us = (unsigned short*)(bias49 + NL * NH * 49);
  unsigned short* hb   = us;                              // 4096*256
  unsigned short* umb  = hb  + (size_t)ROWS * E;          // 4096*288
  unsigned short* qkvb = umb + (size_t)ROWS * (E + E1D);  // 4096*1536
  unsigned short* ob   = qkvb + (size_t)ROWS * 3 * DM;    // 4096*512
  unsigned short* t1b  = ob  + (size_t)ROWS * DM;         // 4096*1024
  unsigned short* qkvT = t1b + (size_t)ROWS * FF;         // 8*1536*256
  unsigned short* WoT  = qkvT + (size_t)NL * 3 * DM * E;  // 8*256*512
  unsigned short* W1T  = WoT  + (size_t)NL * E * DM;      // 8*1024*288
  unsigned short* W2T  = W1T  + (size_t)NL * FF * (E+E1D);// 8*256*1024
  float* tmp = t0;            // layer-loop scratch aliases t0
  float* t1f = (float*)t1b;   // head scratch aliases t1b

  // ---- weight transpose+convert (4 launches) ----
  transpose_qkv<<<dim3(DM/32, E/32, 3*NL), 256, 0, stream>>>(Wq, Wk, Wv, qkvT);
  transpose_bf16<<<dim3(E/32, DM/32, NL), 256, 0, stream>>>(
      Wo, WoT, DM, E, (size_t)DM * E, (size_t)DM * E);
  transpose_bf16<<<dim3(FF/32, (E+E1D)/32, NL), 256, 0, stream>>>(
      W1, W1T, E + E1D, FF, (size_t)(E+E1D) * FF, (size_t)(E+E1D) * FF);
  transpose_bf16<<<dim3(E/32, FF/32, NL), 256, 0, stream>>>(
      W2, W2T, FF, E, (size_t)FF * E, (size_t)FF * E);

  embed1_kernel<<<ROWS, 256, 0, stream>>>(z, x, aa, ex_w1, ex_b1, t0, umb);
  gemm64f<false,true,true><<<dim3(E/64, ROWS/64), 256, 0, stream>>>(
      t0, ex_w2, ex_b2, h, hb, E, E);
  bias_kernel<<<NL, 256, 0, stream>>>(pos, W2d, b2d, bias49);

  for (int i = 0; i < NL; ++i) {
    // fused QKV: N=1536, 64x128 tiles (768 blocks), q-scale on cols<512
    gemm_mfma<64,128,false,false,true,true><<<dim3(12, 64), 256, 0, stream>>>(
        hb, qkvT + (size_t)i * 3 * DM * E, nullptr, nullptr, qkvb, 3 * DM, E);
    attn_kernel<<<dim3(Ln/64, Bn*NH), 256, 0, stream>>>(
        qkvb, bias49 + (size_t)i * NH * 49, ob);
    // Wo + bias + resid(h) -> tmp fp32  (flat 1024, XCD-swizzled)
    gemm_n256<<<1024, 256, 0, stream>>>(
        ob, WoT + (size_t)i * DM * E, bo + (size_t)i * E, h, tmp, DM);
    ln_kernel<<<ROWS, 256, 0, stream>>>(tmp, g1 + (size_t)i * E, be1 + (size_t)i * E, h, umb, E + E1D);
    // FF1 + bias + relu -> bf16 t1b  (64x128 tiles, 512 blocks)
    gemm_mfma<64,128,true,true,true,false><<<dim3(FF/128, 64), 256, 0, stream>>>(
        umb, W1T + (size_t)i * FF * (E+E1D), b1 + (size_t)i * FF, nullptr, t1b, FF, E + E1D);
    // FF2 + bias + resid(h) -> tmp fp32  (flat 1024, XCD-swizzled)
    gemm_n256<<<1024, 256, 0, stream>>>(
        t1b, W2T + (size_t)i * E * FF, b2 + (size_t)i * E, h, tmp, FF);
    ln_kernel<<<ROWS, 256, 0, stream>>>(tmp, g2 + (size_t)i * E, be2 + (size_t)i * E, h, hb, E);
  }

  // fp32 head
  gemm64f<true,true,false><<<dim3(E/64, ROWS/64), 256, 0, stream>>>(
      h, m3w1, m3b1, t1f, nullptr, E, E);
  final_r_kernel<<<ROWS, 256, 0, stream>>>(t1f, m3w2, m3b2, r);
  dist_kernel<<<ROWS, 512, 0, stream>>>(r, (float*)d_out);
}

// Round 10
// 913.265 us; speedup vs baseline: 1.0841x; 1.0841x over previous
//
#include <hip/hip_runtime.h>
#include <math.h>

constexpr int Bn = 8, NZ = 16, Ln = 512;
constexpr int E = 256, DM = 512, NH = 16, HD = 32;
constexpr int FF = 1024, NL = 8, E1D = 32, PDIM = 64, PMAX = 24;
constexpr int ROWS = Bn * Ln;                       // 4096
constexpr float QSCALE = 0.04419417382415922f;      // 1/sqrt(512)

typedef __attribute__((ext_vector_type(8))) short bf16x8;
typedef __attribute__((ext_vector_type(4))) float floatx4;

__device__ inline unsigned short f2b(float f) {
  union { float f; unsigned u; } v; v.f = f;
  unsigned r = (v.u + 0x7FFF + ((v.u >> 16) & 1)) >> 16;
  return (unsigned short)r;
}
__device__ inline float b2f(unsigned short u) {
  union { unsigned u; float f; } v; v.u = ((unsigned)u) << 16; return v.f;
}

// ---------------------------------------------------------------------------
// batched Wq/Wk/Wv fp32 [l][E][DM] -> bf16 qkvT [l][3*DM][E]
// ---------------------------------------------------------------------------
__global__ __launch_bounds__(256) void transpose_qkv(
    const float* __restrict__ Wq, const float* __restrict__ Wk,
    const float* __restrict__ Wv, unsigned short* __restrict__ qkvT)
{
  __shared__ float t[32][33];
  int zb = blockIdx.z;
  int which = zb / NL, l = zb % NL;
  const float* s = (which == 0 ? Wq : which == 1 ? Wk : Wv) + (size_t)l * E * DM;
  unsigned short* d = qkvT + (size_t)l * 3 * DM * E + (size_t)which * DM * E;
  int c0 = blockIdx.x * 32, r0 = blockIdx.y * 32;
  int tx = threadIdx.x & 31, ty = threadIdx.x >> 5;
  #pragma unroll
  for (int i = 0; i < 4; ++i)
    t[ty + i * 8][tx] = s[(size_t)(r0 + ty + i * 8) * DM + c0 + tx];
  __syncthreads();
  #pragma unroll
  for (int i = 0; i < 4; ++i)
    d[(size_t)(c0 + ty + i * 8) * E + r0 + tx] = f2b(t[tx][ty + i * 8]);
}

// ---------------------------------------------------------------------------
// generic fp32 [l][R][C] -> bf16 [l][C][R]
// ---------------------------------------------------------------------------
__global__ __launch_bounds__(256) void transpose_bf16(
    const float* __restrict__ src, unsigned short* __restrict__ dst,
    int R, int C, size_t sls, size_t dls)
{
  __shared__ float t[32][33];
  int l = blockIdx.z;
  int c0 = blockIdx.x * 32, r0 = blockIdx.y * 32;
  int tx = threadIdx.x & 31, ty = threadIdx.x >> 5;
  const float* s = src + (size_t)l * sls;
  unsigned short* d = dst + (size_t)l * dls;
  #pragma unroll
  for (int i = 0; i < 4; ++i)
    t[ty + i * 8][tx] = s[(size_t)(r0 + ty + i * 8) * C + c0 + tx];
  __syncthreads();
  #pragma unroll
  for (int i = 0; i < 4; ++i)
    d[(size_t)(c0 + ty + i * 8) * R + r0 + tx] = f2b(t[tx][ty + i * 8]);
}

// ---------------------------------------------------------------------------
// embed stage 1: t0 = relu(z^T @ ex_w1 + b1) fp32; e_aa gather into umb
// ---------------------------------------------------------------------------
__global__ __launch_bounds__(256) void embed1_kernel(
    const float* __restrict__ z, const float* __restrict__ x,
    const float* __restrict__ aa,
    const float* __restrict__ w1, const float* __restrict__ b1,
    float* __restrict__ t0, unsigned short* __restrict__ umb)
{
  int row = blockIdx.x;
  int b = row >> 9, l = row & (Ln - 1);
  int t = threadIdx.x;
  __shared__ float zs[NZ];
  __shared__ int am_s;
  if (t < NZ) zs[t] = z[((size_t)b * NZ + t) * Ln + l];
  if (t == 0) {
    const float* xp = x + (size_t)b * 20 * Ln + l;
    int am = 0; float bv = xp[0];
    for (int c = 1; c < 20; ++c) { float vv = xp[(size_t)c * Ln]; if (vv > bv) { bv = vv; am = c; } }
    am_s = am;
  }
  __syncthreads();
  float a1 = b1[t];
  #pragma unroll
  for (int nz = 0; nz < NZ; ++nz) a1 += zs[nz] * w1[nz * E + t];
  t0[(size_t)row * E + t] = fmaxf(a1, 0.f);
  if (t < E1D) umb[(size_t)row * (E + E1D) + E + t] = f2b(aa[am_s * E1D + t]);
}

// ---------------------------------------------------------------------------
// pairwise-bias collapse: 49 bins per (layer, head)
// ---------------------------------------------------------------------------
__global__ __launch_bounds__(256) void bias_kernel(
    const float* __restrict__ pos, const float* __restrict__ W2d,
    const float* __restrict__ b2d, float* __restrict__ bias49)
{
  int layer = blockIdx.x;
  for (int idx = threadIdx.x; idx < NH * 49; idx += 256) {
    int hh = idx / 49, bin = idx % 49;
    float acc = b2d[layer * NH + hh];
    for (int p = 0; p < PDIM; ++p)
      acc += pos[bin * PDIM + p] * W2d[((size_t)layer * PDIM + p) * NH + hh];
    bias49[(size_t)layer * NH * 49 + hh * 49 + bin] = acc;
  }
}

// ---------------------------------------------------------------------------
// bf16 MFMA GEMM (128x128 tiles, BK=32) — R8-proven version, no prefetch.
// used for QKV (N=1536,K=256) and FF1 (N=1024,K=288)
// ---------------------------------------------------------------------------
template<int BM, int BN, bool BIAS, bool RELU, bool OUTBF16, bool QKV>
__global__ __launch_bounds__(256) void gemm_mfma(
    const unsigned short* __restrict__ A, const unsigned short* __restrict__ Bt,
    const float* __restrict__ bias,
    float* __restrict__ Cf, unsigned short* __restrict__ Cb, int N, int K)
{
  constexpr int MT = BM / 32, NT = BN / 32;
  __shared__ __align__(16) unsigned short As[BM][40];
  __shared__ __align__(16) unsigned short Bs[BN][40];
  const int tid = threadIdx.x;
  const int wave = tid >> 6, ln = tid & 63;
  const int quad = ln >> 4, l16 = ln & 15;
  const int wm = wave >> 1, wn = wave & 1;
  const int m0 = blockIdx.y * BM, n0 = blockIdx.x * BN;

  floatx4 acc[MT][NT] = {};

  for (int kb = 0; kb < K; kb += 32) {
    __syncthreads();
    #pragma unroll
    for (int it = 0; it < BM / 64; ++it) {
      int c = tid + it * 256;
      int row = c >> 2, cc = (c & 3) * 8;
      *(float4*)&As[row][cc] = *(const float4*)(A + (size_t)(m0 + row) * K + kb + cc);
    }
    #pragma unroll
    for (int it = 0; it < BN / 64; ++it) {
      int c = tid + it * 256;
      int row = c >> 2, cc = (c & 3) * 8;
      *(float4*)&Bs[row][cc] = *(const float4*)(Bt + (size_t)(n0 + row) * K + kb + cc);
    }
    __syncthreads();
    bf16x8 af[MT], bfr[NT];
    #pragma unroll
    for (int i = 0; i < MT; ++i)
      af[i] = *(const bf16x8*)&As[wm * (BM / 2) + i * 16 + l16][quad * 8];
    #pragma unroll
    for (int j = 0; j < NT; ++j)
      bfr[j] = *(const bf16x8*)&Bs[wn * (BN / 2) + j * 16 + l16][quad * 8];
    #pragma unroll
    for (int i = 0; i < MT; ++i)
      #pragma unroll
      for (int j = 0; j < NT; ++j)
        acc[i][j] = __builtin_amdgcn_mfma_f32_16x16x32_bf16(af[i], bfr[j], acc[i][j], 0, 0, 0);
  }

  #pragma unroll
  for (int i = 0; i < MT; ++i)
    #pragma unroll
    for (int j = 0; j < NT; ++j) {
      int col = n0 + wn * (BN / 2) + j * 16 + l16;
      float bv = BIAS ? bias[col] : 0.f;
      float sc = QKV ? (col < 512 ? QSCALE : 1.f) : 1.f;
      #pragma unroll
      for (int r = 0; r < 4; ++r) {
        int rowg = m0 + wm * (BM / 2) + i * 16 + quad * 4 + r;
        float v = acc[i][j][r] * sc + bv;
        if (RELU) v = fmaxf(v, 0.f);
        if (OUTBF16) Cb[(size_t)rowg * N + col] = f2b(v);
        else Cf[(size_t)rowg * N + col] = v;
      }
    }
}

// ---------------------------------------------------------------------------
// N=256 GEMM: BM=BN=32, BK=64, grid (8,128)=1024 blocks (R8's proven shape),
// staging via global_load_lds 16B DMA (m97 technique). LDS is unpadded
// [32][64] with XOR chunk swizzle (chunk ^= row&7): staging stays
// tid-contiguous (DMA-legal), frag ds_read_b128 gets free 2-way banking.
// Chunk placement only — values & accumulation order bitwise identical.
// ---------------------------------------------------------------------------
__global__ __launch_bounds__(256) void gemm_n256(
    const unsigned short* __restrict__ A, const unsigned short* __restrict__ Bt,
    const float* __restrict__ bias, const float* __restrict__ resid,
    float* __restrict__ Cf, int K)
{
  __shared__ __align__(16) unsigned short As[32 * 64];
  __shared__ __align__(16) unsigned short Bs[32 * 64];
  const int tid = threadIdx.x;
  const int wave = tid >> 6, ln = tid & 63;
  const int quad = ln >> 4, l16 = ln & 15;
  const int wm = wave >> 1, wn = wave & 1;
  const int m0 = blockIdx.y * 32, n0 = blockIdx.x * 32;
  const int srow = tid >> 3;
  const int schunk = (tid & 7) ^ (srow & 7);       // swizzled source chunk
  const unsigned short* ga = A + (size_t)(m0 + srow) * K + schunk * 8;
  const unsigned short* gb = Bt + (size_t)(n0 + srow) * K + schunk * 8;
  unsigned short* la = As + tid * 8;               // 16B/lane, tid-contiguous
  unsigned short* lb = Bs + tid * 8;

  floatx4 acc = {};

  for (int kb = 0; kb < K; kb += 64) {
    __syncthreads();
    __builtin_amdgcn_global_load_lds(
        (const __attribute__((address_space(1))) unsigned int*)(const void*)(ga + kb),
        (__attribute__((address_space(3))) unsigned int*)(void*)la, 16, 0, 0);
    __builtin_amdgcn_global_load_lds(
        (const __attribute__((address_space(1))) unsigned int*)(const void*)(gb + kb),
        (__attribute__((address_space(3))) unsigned int*)(void*)lb, 16, 0, 0);
    __syncthreads();
    #pragma unroll
    for (int kc = 0; kc < 2; ++kc) {
      int ca = (kc * 4 + quad) ^ (l16 & 7);
      bf16x8 af = *(const bf16x8*)(As + (wm * 16 + l16) * 64 + ca * 8);
      bf16x8 bf = *(const bf16x8*)(Bs + (wn * 16 + l16) * 64 + ca * 8);
      acc = __builtin_amdgcn_mfma_f32_16x16x32_bf16(af, bf, acc, 0, 0, 0);
    }
  }

  const int col = n0 + wn * 16 + l16;
  const float bv = bias[col];
  #pragma unroll
  for (int r = 0; r < 4; ++r) {
    int rowg = m0 + wm * 16 + quad * 4 + r;
    Cf[(size_t)rowg * 256 + col] = acc[r] + bv + resid[(size_t)rowg * 256 + col];
  }
}

// ---------------------------------------------------------------------------
// MFMA flash attention (unchanged — verified)
// ---------------------------------------------------------------------------
__global__ __launch_bounds__(256) void attn_kernel(
    const unsigned short* __restrict__ qkv, const float* __restrict__ bias49,
    unsigned short* __restrict__ o)
{
  const int i0 = blockIdx.x * 64;
  const int bh = blockIdx.y;
  const int b = bh >> 4, hh = bh & 15;
  const int tid = threadIdx.x;
  const int wave = tid >> 6, ln = tid & 63;
  const int quad = ln >> 4, l16 = ln & 15;

  __shared__ __align__(16) unsigned short Kt[64][40];
  __shared__ __align__(16) unsigned short Vt[32][72];
  __shared__ __align__(16) unsigned short Pw[4][2][16][72];
  __shared__ float bsh[49];

  if (tid < 49) bsh[tid] = bias49[hh * 49 + tid];

  const unsigned short* qkvb = qkv + (size_t)b * Ln * 1536;

  const int qrow = i0 + wave * 16 + l16;
  const bf16x8 qf = *(const bf16x8*)(qkvb + (size_t)qrow * 1536 + hh * 32 + quad * 8);

  float m[4], l[4];
  #pragma unroll
  for (int r = 0; r < 4; ++r) { m[r] = -1e30f; l[r] = 0.f; }
  floatx4 acc_o[2] = {};

  const int krow = tid >> 2, kch = (tid & 3) * 8;
  const int vkey = tid & 63, vch = (tid >> 6) * 8;

  for (int jt = 0; jt < 8; ++jt) {
    const int j0 = jt * 64;
    __syncthreads();
    *(float4*)&Kt[krow][kch] =
        *(const float4*)(qkvb + (size_t)(j0 + krow) * 1536 + 512 + hh * 32 + kch);
    bf16x8 vv = *(const bf16x8*)(qkvb + (size_t)(j0 + vkey) * 1536 + 1024 + hh * 32 + vch);
    #pragma unroll
    for (int i = 0; i < 8; ++i) Vt[vch + i][vkey] = (unsigned short)vv[i];
    __syncthreads();

    floatx4 s4[4];
    #pragma unroll
    for (int t = 0; t < 4; ++t) {
      bf16x8 kf = *(const bf16x8*)&Kt[16 * t + l16][quad * 8];
      s4[t] = __builtin_amdgcn_mfma_f32_16x16x32_bf16(qf, kf, (floatx4){0.f, 0.f, 0.f, 0.f}, 0, 0, 0);
    }
    const int relmin = j0 - (i0 + 63), relmax = j0 + 63 - i0;
    if (relmin >= PMAX) {
      float bc = bsh[48];
      #pragma unroll
      for (int t = 0; t < 4; ++t)
        #pragma unroll
        for (int r = 0; r < 4; ++r) s4[t][r] += bc;
    } else if (relmax <= -PMAX) {
      float bc = bsh[0];
      #pragma unroll
      for (int t = 0; t < 4; ++t)
        #pragma unroll
        for (int r = 0; r < 4; ++r) s4[t][r] += bc;
    } else {
      const int base_rel = (j0 + l16) - (i0 + wave * 16 + quad * 4);
      #pragma unroll
      for (int t = 0; t < 4; ++t)
        #pragma unroll
        for (int r = 0; r < 4; ++r) {
          int rel = base_rel + 16 * t - r;
          rel = rel < -PMAX ? -PMAX : (rel > PMAX ? PMAX : rel);
          s4[t][r] += bsh[rel + PMAX];
        }
    }

    float mloc[4], alpha[4], psum[4];
    #pragma unroll
    for (int r = 0; r < 4; ++r) {
      mloc[r] = fmaxf(fmaxf(s4[0][r], s4[1][r]), fmaxf(s4[2][r], s4[3][r]));
      #pragma unroll
      for (int off = 1; off < 16; off <<= 1)
        mloc[r] = fmaxf(mloc[r], __shfl_xor(mloc[r], off, 64));
      float mnew = fmaxf(m[r], mloc[r]);
      alpha[r] = __expf(m[r] - mnew);
      m[r] = mnew;
      psum[r] = 0.f;
    }
    #pragma unroll
    for (int t = 0; t < 4; ++t)
      #pragma unroll
      for (int r = 0; r < 4; ++r) {
        float p = __expf(s4[t][r] - m[r]);
        s4[t][r] = p;
        psum[r] += p;
      }
    #pragma unroll
    for (int r = 0; r < 4; ++r) {
      #pragma unroll
      for (int off = 1; off < 16; off <<= 1)
        psum[r] += __shfl_xor(psum[r], off, 64);
      l[r] = l[r] * alpha[r] + psum[r];
      acc_o[0][r] *= alpha[r];
      acc_o[1][r] *= alpha[r];
    }

    #pragma unroll
    for (int t = 0; t < 4; ++t)
      #pragma unroll
      for (int r = 0; r < 4; ++r) {
        float p = s4[t][r];
        unsigned short hi = f2b(p);
        unsigned short lo = f2b(p - b2f(hi));
        Pw[wave][0][quad * 4 + r][16 * t + l16] = hi;
        Pw[wave][1][quad * 4 + r][16 * t + l16] = lo;
      }

    #pragma unroll
    for (int kh = 0; kh < 2; ++kh) {
      bf16x8 phi = *(const bf16x8*)&Pw[wave][0][l16][kh * 32 + quad * 8];
      bf16x8 plo = *(const bf16x8*)&Pw[wave][1][l16][kh * 32 + quad * 8];
      #pragma unroll
      for (int nt = 0; nt < 2; ++nt) {
        bf16x8 vf = *(const bf16x8*)&Vt[nt * 16 + l16][kh * 32 + quad * 8];
        acc_o[nt] = __builtin_amdgcn_mfma_f32_16x16x32_bf16(phi, vf, acc_o[nt], 0, 0, 0);
        acc_o[nt] = __builtin_amdgcn_mfma_f32_16x16x32_bf16(plo, vf, acc_o[nt], 0, 0, 0);
      }
    }
  }

  #pragma unroll
  for (int r = 0; r < 4; ++r) {
    float inv = 1.f / l[r];
    size_t rowg = (size_t)b * Ln + i0 + wave * 16 + quad * 4 + r;
    #pragma unroll
    for (int nt = 0; nt < 2; ++nt)
      o[rowg * 512 + hh * 32 + nt * 16 + l16] = f2b(acc_o[nt][r] * inv);
  }
}

// ---------------------------------------------------------------------------
// LayerNorm over E=256; writes h (fp32) and a bf16 mirror with given stride
// ---------------------------------------------------------------------------
__global__ __launch_bounds__(256) void ln_kernel(
    const float* __restrict__ xin, const float* __restrict__ g,
    const float* __restrict__ be, float* __restrict__ hout,
    unsigned short* __restrict__ bout, int bstride)
{
  int row = blockIdx.x, t = threadIdx.x;
  float v = xin[(size_t)row * E + t];
  float s = v;
  #pragma unroll
  for (int off = 32; off > 0; off >>= 1) s += __shfl_down(s, off, 64);
  __shared__ float ws4[4];
  __shared__ float mbc, rbc;
  if ((t & 63) == 0) ws4[t >> 6] = s;
  __syncthreads();
  if (t == 0) mbc = (ws4[0] + ws4[1] + ws4[2] + ws4[3]) * (1.f / E);
  __syncthreads();
  float m = mbc;
  float d = v - m;
  float s2 = d * d;
  #pragma unroll
  for (int off = 32; off > 0; off >>= 1) s2 += __shfl_down(s2, off, 64);
  if ((t & 63) == 0) ws4[t >> 6] = s2;
  __syncthreads();
  if (t == 0) rbc = rsqrtf((ws4[0] + ws4[1] + ws4[2] + ws4[3]) * (1.f / E) + 1e-5f);
  __syncthreads();
  float y = d * rbc * g[t] + be[t];
  hout[(size_t)row * E + t] = y;
  bout[(size_t)row * bstride + t] = f2b(y);
}

// ---------------------------------------------------------------------------
// fp32 tiled GEMM: C = act(A@B + bias), optional bf16 mirror (embed2 / head)
// ---------------------------------------------------------------------------
template<bool RELU, bool BIAS, bool MIRROR>
__global__ __launch_bounds__(256) void gemm64f(
    const float* __restrict__ A, const float* __restrict__ B,
    const float* __restrict__ bias, float* __restrict__ C,
    unsigned short* __restrict__ mir, int N, int K)
{
  __shared__ __align__(16) float As[16][64];
  __shared__ __align__(16) float Bss[16][68];
  const int tid = threadIdx.x;
  const int tx = tid & 15, ty = tid >> 4;
  const int m0 = blockIdx.y * 64, n0 = blockIdx.x * 64;
  const int arow = tid >> 2, acol = (tid & 3) * 4;
  const int brow = tid >> 6, bcol = tid & 63;
  float acc[4][4] = {};
  for (int kb = 0; kb < K; kb += 16) {
    __syncthreads();
    float4 av = *(const float4*)(A + (size_t)(m0 + arow) * K + kb + acol);
    As[acol + 0][arow] = av.x; As[acol + 1][arow] = av.y;
    As[acol + 2][arow] = av.z; As[acol + 3][arow] = av.w;
    #pragma unroll
    for (int kk = 0; kk < 4; ++kk)
      Bss[brow + kk * 4][bcol] = B[(size_t)(kb + brow + kk * 4) * N + n0 + bcol];
    __syncthreads();
    #pragma unroll
    for (int k = 0; k < 16; ++k) {
      float4 a = *(const float4*)&As[k][4 * ty];
      float4 b = *(const float4*)&Bss[k][4 * tx];
      float av4[4] = {a.x, a.y, a.z, a.w};
      float bv4[4] = {b.x, b.y, b.z, b.w};
      #pragma unroll
      for (int ii = 0; ii < 4; ++ii)
        #pragma unroll
        for (int jj = 0; jj < 4; ++jj)
          acc[ii][jj] += av4[ii] * bv4[jj];
    }
  }
  #pragma unroll
  for (int ii = 0; ii < 4; ++ii) {
    size_t row = (size_t)m0 + 4 * ty + ii;
    int col = n0 + 4 * tx;
    float4 vv;
    vv.x = acc[ii][0]; vv.y = acc[ii][1]; vv.z = acc[ii][2]; vv.w = acc[ii][3];
    if (BIAS) {
      float4 bb = *(const float4*)(bias + col);
      vv.x += bb.x; vv.y += bb.y; vv.z += bb.z; vv.w += bb.w;
    }
    if (RELU) {
      vv.x = fmaxf(vv.x, 0.f); vv.y = fmaxf(vv.y, 0.f);
      vv.z = fmaxf(vv.z, 0.f); vv.w = fmaxf(vv.w, 0.f);
    }
    *(float4*)(C + row * N + col) = vv;
    if (MIRROR) {
      ushort4 mv;
      mv.x = f2b(vv.x); mv.y = f2b(vv.y); mv.z = f2b(vv.z); mv.w = f2b(vv.w);
      *(ushort4*)(mir + row * N + col) = mv;
    }
  }
}

__global__ __launch_bounds__(256) void final_r_kernel(
    const float* __restrict__ t1, const float* __restrict__ w2,
    const float* __restrict__ b2, float* __restrict__ r)
{
  int row = blockIdx.x, t = threadIdx.x;
  float xv = t1[(size_t)row * E + t];
  float p0 = xv * w2[t * 3 + 0];
  float p1 = xv * w2[t * 3 + 1];
  float p2 = xv * w2[t * 3 + 2];
  #pragma unroll
  for (int off = 32; off > 0; off >>= 1) {
    p0 += __shfl_down(p0, off, 64);
    p1 += __shfl_down(p1, off, 64);
    p2 += __shfl_down(p2, off, 64);
  }
  __shared__ float red[4][3];
  if ((t & 63) == 0) { int w = t >> 6; red[w][0] = p0; red[w][1] = p1; red[w][2] = p2; }
  __syncthreads();
  if (t < 3)
    r[(size_t)row * 3 + t] = red[0][t] + red[1][t] + red[2][t] + red[3][t] + b2[t];
}

__global__ __launch_bounds__(512) void dist_kernel(
    const float* __restrict__ r, float* __restrict__ out)
{
  int bi = blockIdx.x;
  int j = threadIdx.x;
  int b = bi >> 9;
  float x0 = r[(size_t)bi * 3 + 0];
  float y0 = r[(size_t)bi * 3 + 1];
  float z0 = r[(size_t)bi * 3 + 2];
  const float* rj = r + ((size_t)b * Ln + j) * 3;
  float dx = rj[0] - x0, dy = rj[1] - y0, dz = rj[2] - z0;
  out[(size_t)bi * Ln + j] = sqrtf(dx * dx + dy * dy + dz * dz + 1e-12f);
}

// ---------------------------------------------------------------------------
extern "C" void kernel_launch(void* const* d_in, const int* in_sizes, int n_in,
                              void* d_out, int out_size, void* d_ws, size_t ws_size,
                              hipStream_t stream)
{
  const float* z     = (const float*)d_in[0];
  const float* x     = (const float*)d_in[1];
  const float* pos   = (const float*)d_in[2];
  const float* aa    = (const float*)d_in[3];
  const float* ex_w1 = (const float*)d_in[4];
  const float* ex_b1 = (const float*)d_in[5];
  const float* ex_w2 = (const float*)d_in[6];
  const float* ex_b2 = (const float*)d_in[7];
  const float* Wq    = (const float*)d_in[8];
  const float* Wk    = (const float*)d_in[9];
  const float* Wv    = (const float*)d_in[10];
  const float* Wo    = (const float*)d_in[11];
  const float* bo    = (const float*)d_in[12];
  const float* W2d   = (const float*)d_in[13];
  const float* b2d   = (const float*)d_in[14];
  const float* W1    = (const float*)d_in[15];
  const float* b1    = (const float*)d_in[16];
  const float* W2    = (const float*)d_in[17];
  const float* b2    = (const float*)d_in[18];
  const float* g1    = (const float*)d_in[19];
  const float* be1   = (const float*)d_in[20];
  const float* g2    = (const float*)d_in[21];
  const float* be2   = (const float*)d_in[22];
  const float* m3w1  = (const float*)d_in[23];
  const float* m3b1  = (const float*)d_in[24];
  const float* m3w2  = (const float*)d_in[25];
  const float* m3b2  = (const float*)d_in[26];

  float* ws     = (float*)d_ws;
  float* h      = ws;                          // 4096*256
  float* t0     = h + (size_t)ROWS * E;        // 4096*256 (embed hidden / tmp)
  float* r      = t0 + (size_t)ROWS * E;       // 4096*3
  float* bias49 = r + (size_t)ROWS * 3;        // 8*16*49
  unsigned short* us = (unsigned short*)(bias49 + NL * NH * 49);
  unsigned short* hb   = us;                              // 4096*256
  unsigned short* umb  = hb  + (size_t)ROWS * E;          // 4096*288
  unsigned short* qkvb = umb + (size_t)ROWS * (E + E1D);  // 4096*1536
  unsigned short* ob   = qkvb + (size_t)ROWS * 3 * DM;    // 4096*512
  unsigned short* t1b  = ob  + (size_t)ROWS * DM;         // 4096*1024
  unsigned short* qkvT = t1b + (size_t)ROWS * FF;         // 8*1536*256
  unsigned short* WoT  = qkvT + (size_t)NL * 3 * DM * E;  // 8*256*512
  unsigned short* W1T  = WoT  + (size_t)NL * E * DM;      // 8*1024*288
  unsigned short* W2T  = W1T  + (size_t)NL * FF * (E+E1D);// 8*256*1024
  float* tmp = t0;            // layer-loop scratch aliases t0
  float* t1f = (float*)t1b;   // head scratch aliases t1b

  // ---- weight transpose+convert (4 launches) ----
  transpose_qkv<<<dim3(DM/32, E/32, 3*NL), 256, 0, stream>>>(Wq, Wk, Wv, qkvT);
  transpose_bf16<<<dim3(E/32, DM/32, NL), 256, 0, stream>>>(
      Wo, WoT, DM, E, (size_t)DM * E, (size_t)DM * E);
  transpose_bf16<<<dim3(FF/32, (E+E1D)/32, NL), 256, 0, stream>>>(
      W1, W1T, E + E1D, FF, (size_t)(E+E1D) * FF, (size_t)(E+E1D) * FF);
  transpose_bf16<<<dim3(E/32, FF/32, NL), 256, 0, stream>>>(
      W2, W2T, FF, E, (size_t)FF * E, (size_t)FF * E);

  embed1_kernel<<<ROWS, 256, 0, stream>>>(z, x, aa, ex_w1, ex_b1, t0, umb);
  gemm64f<false,true,true><<<dim3(E/64, ROWS/64), 256, 0, stream>>>(
      t0, ex_w2, ex_b2, h, hb, E, E);
  bias_kernel<<<NL, 256, 0, stream>>>(pos, W2d, b2d, bias49);

  for (int i = 0; i < NL; ++i) {
    // fused QKV: N=1536, 128x128 tiles, q-scale on cols<512, bf16 out
    gemm_mfma<128,128,false,false,true,true><<<dim3(12, 32), 256, 0, stream>>>(
        hb, qkvT + (size_t)i * 3 * DM * E, nullptr, nullptr, qkvb, 3 * DM, E);
    attn_kernel<<<dim3(Ln/64, Bn*NH), 256, 0, stream>>>(
        qkvb, bias49 + (size_t)i * NH * 49, ob);
    // Wo + bias + resid(h) -> tmp fp32  (1024 blocks, global_load_lds staging)
    gemm_n256<<<dim3(E/32, ROWS/32), 256, 0, stream>>>(
        ob, WoT + (size_t)i * DM * E, bo + (size_t)i * E, h, tmp, DM);
    ln_kernel<<<ROWS, 256, 0, stream>>>(tmp, g1 + (size_t)i * E, be1 + (size_t)i * E, h, umb, E + E1D);
    // FF1 + bias + relu -> bf16 t1b
    gemm_mfma<128,128,true,true,true,false><<<dim3(FF/128, ROWS/128), 256, 0, stream>>>(
        umb, W1T + (size_t)i * FF * (E+E1D), b1 + (size_t)i * FF, nullptr, t1b, FF, E + E1D);
    // FF2 + bias + resid(h) -> tmp fp32  (1024 blocks, global_load_lds staging)
    gemm_n256<<<dim3(E/32, ROWS/32), 256, 0, stream>>>(
        t1b, W2T + (size_t)i * E * FF, b2 + (size_t)i * E, h, tmp, FF);
    ln_kernel<<<ROWS, 256, 0, stream>>>(tmp, g2 + (size_t)i * E, be2 + (size_t)i * E, h, hb, E);
  }

  // fp32 head
  gemm64f<true,true,false><<<dim3(E/64, ROWS/64), 256, 0, stream>>>(
      h, m3w1, m3b1, t1f, nullptr, E, E);
  final_r_kernel<<<ROWS, 256, 0, stream>>>(t1f, m3w2, m3b2, r);
  dist_kernel<<<ROWS, 512, 0, stream>>>(r, (float*)d_out);
}

// Round 11
// 875.678 us; speedup vs baseline: 1.1306x; 1.0429x over previous
//
#include <hip/hip_runtime.h>
#include <math.h>

constexpr int Bn = 8, NZ = 16, Ln = 512;
constexpr int E = 256, DM = 512, NH = 16, HD = 32;
constexpr int FF = 1024, NL = 8, E1D = 32, PDIM = 64, PMAX = 24;
constexpr int ROWS = Bn * Ln;                       // 4096
constexpr float QSCALE = 0.04419417382415922f;      // 1/sqrt(512)

typedef __attribute__((ext_vector_type(8))) short bf16x8;
typedef __attribute__((ext_vector_type(4))) float floatx4;

__device__ inline unsigned short f2b(float f) {
  union { float f; unsigned u; } v; v.f = f;
  unsigned r = (v.u + 0x7FFF + ((v.u >> 16) & 1)) >> 16;
  return (unsigned short)r;
}
__device__ inline float b2f(unsigned short u) {
  union { unsigned u; float f; } v; v.u = ((unsigned)u) << 16; return v.f;
}

// ---------------------------------------------------------------------------
// batched Wq/Wk/Wv fp32 [l][E][DM] -> bf16 qkvT [l][3*DM][E]
// ---------------------------------------------------------------------------
__global__ __launch_bounds__(256) void transpose_qkv(
    const float* __restrict__ Wq, const float* __restrict__ Wk,
    const float* __restrict__ Wv, unsigned short* __restrict__ qkvT)
{
  __shared__ float t[32][33];
  int zb = blockIdx.z;
  int which = zb / NL, l = zb % NL;
  const float* s = (which == 0 ? Wq : which == 1 ? Wk : Wv) + (size_t)l * E * DM;
  unsigned short* d = qkvT + (size_t)l * 3 * DM * E + (size_t)which * DM * E;
  int c0 = blockIdx.x * 32, r0 = blockIdx.y * 32;
  int tx = threadIdx.x & 31, ty = threadIdx.x >> 5;
  #pragma unroll
  for (int i = 0; i < 4; ++i)
    t[ty + i * 8][tx] = s[(size_t)(r0 + ty + i * 8) * DM + c0 + tx];
  __syncthreads();
  #pragma unroll
  for (int i = 0; i < 4; ++i)
    d[(size_t)(c0 + ty + i * 8) * E + r0 + tx] = f2b(t[tx][ty + i * 8]);
}

// ---------------------------------------------------------------------------
// generic fp32 [l][R][C] -> bf16 [l][C][R]
// ---------------------------------------------------------------------------
__global__ __launch_bounds__(256) void transpose_bf16(
    const float* __restrict__ src, unsigned short* __restrict__ dst,
    int R, int C, size_t sls, size_t dls)
{
  __shared__ float t[32][33];
  int l = blockIdx.z;
  int c0 = blockIdx.x * 32, r0 = blockIdx.y * 32;
  int tx = threadIdx.x & 31, ty = threadIdx.x >> 5;
  const float* s = src + (size_t)l * sls;
  unsigned short* d = dst + (size_t)l * dls;
  #pragma unroll
  for (int i = 0; i < 4; ++i)
    t[ty + i * 8][tx] = s[(size_t)(r0 + ty + i * 8) * C + c0 + tx];
  __syncthreads();
  #pragma unroll
  for (int i = 0; i < 4; ++i)
    d[(size_t)(c0 + ty + i * 8) * R + r0 + tx] = f2b(t[tx][ty + i * 8]);
}

// ---------------------------------------------------------------------------
// embed stage 1: t0 = relu(z^T @ ex_w1 + b1) fp32; e_aa gather into umb
// ---------------------------------------------------------------------------
__global__ __launch_bounds__(256) void embed1_kernel(
    const float* __restrict__ z, const float* __restrict__ x,
    const float* __restrict__ aa,
    const float* __restrict__ w1, const float* __restrict__ b1,
    float* __restrict__ t0, unsigned short* __restrict__ umb)
{
  int row = blockIdx.x;
  int b = row >> 9, l = row & (Ln - 1);
  int t = threadIdx.x;
  __shared__ float zs[NZ];
  __shared__ int am_s;
  if (t < NZ) zs[t] = z[((size_t)b * NZ + t) * Ln + l];
  if (t == 0) {
    const float* xp = x + (size_t)b * 20 * Ln + l;
    int am = 0; float bv = xp[0];
    for (int c = 1; c < 20; ++c) { float vv = xp[(size_t)c * Ln]; if (vv > bv) { bv = vv; am = c; } }
    am_s = am;
  }
  __syncthreads();
  float a1 = b1[t];
  #pragma unroll
  for (int nz = 0; nz < NZ; ++nz) a1 += zs[nz] * w1[nz * E + t];
  t0[(size_t)row * E + t] = fmaxf(a1, 0.f);
  if (t < E1D) umb[(size_t)row * (E + E1D) + E + t] = f2b(aa[am_s * E1D + t]);
}

// ---------------------------------------------------------------------------
// pairwise-bias collapse: 49 bins per (layer, head)
// ---------------------------------------------------------------------------
__global__ __launch_bounds__(256) void bias_kernel(
    const float* __restrict__ pos, const float* __restrict__ W2d,
    const float* __restrict__ b2d, float* __restrict__ bias49)
{
  int layer = blockIdx.x;
  for (int idx = threadIdx.x; idx < NH * 49; idx += 256) {
    int hh = idx / 49, bin = idx % 49;
    float acc = b2d[layer * NH + hh];
    for (int p = 0; p < PDIM; ++p)
      acc += pos[bin * PDIM + p] * W2d[((size_t)layer * PDIM + p) * NH + hh];
    bias49[(size_t)layer * NH * 49 + hh * 49 + bin] = acc;
  }
}

// ---------------------------------------------------------------------------
// bf16 MFMA GEMM (128x128 tiles, BK=32) — R8-proven version.
// used for QKV (N=1536,K=256) and FF1 (N=1024,K=288)
// ---------------------------------------------------------------------------
template<int BM, int BN, bool BIAS, bool RELU, bool OUTBF16, bool QKV>
__global__ __launch_bounds__(256) void gemm_mfma(
    const unsigned short* __restrict__ A, const unsigned short* __restrict__ Bt,
    const float* __restrict__ bias,
    float* __restrict__ Cf, unsigned short* __restrict__ Cb, int N, int K)
{
  constexpr int MT = BM / 32, NT = BN / 32;
  __shared__ __align__(16) unsigned short As[BM][40];
  __shared__ __align__(16) unsigned short Bs[BN][40];
  const int tid = threadIdx.x;
  const int wave = tid >> 6, ln = tid & 63;
  const int quad = ln >> 4, l16 = ln & 15;
  const int wm = wave >> 1, wn = wave & 1;
  const int m0 = blockIdx.y * BM, n0 = blockIdx.x * BN;

  floatx4 acc[MT][NT] = {};

  for (int kb = 0; kb < K; kb += 32) {
    __syncthreads();
    #pragma unroll
    for (int it = 0; it < BM / 64; ++it) {
      int c = tid + it * 256;
      int row = c >> 2, cc = (c & 3) * 8;
      *(float4*)&As[row][cc] = *(const float4*)(A + (size_t)(m0 + row) * K + kb + cc);
    }
    #pragma unroll
    for (int it = 0; it < BN / 64; ++it) {
      int c = tid + it * 256;
      int row = c >> 2, cc = (c & 3) * 8;
      *(float4*)&Bs[row][cc] = *(const float4*)(Bt + (size_t)(n0 + row) * K + kb + cc);
    }
    __syncthreads();
    bf16x8 af[MT], bfr[NT];
    #pragma unroll
    for (int i = 0; i < MT; ++i)
      af[i] = *(const bf16x8*)&As[wm * (BM / 2) + i * 16 + l16][quad * 8];
    #pragma unroll
    for (int j = 0; j < NT; ++j)
      bfr[j] = *(const bf16x8*)&Bs[wn * (BN / 2) + j * 16 + l16][quad * 8];
    #pragma unroll
    for (int i = 0; i < MT; ++i)
      #pragma unroll
      for (int j = 0; j < NT; ++j)
        acc[i][j] = __builtin_amdgcn_mfma_f32_16x16x32_bf16(af[i], bfr[j], acc[i][j], 0, 0, 0);
  }

  #pragma unroll
  for (int i = 0; i < MT; ++i)
    #pragma unroll
    for (int j = 0; j < NT; ++j) {
      int col = n0 + wn * (BN / 2) + j * 16 + l16;
      float bv = BIAS ? bias[col] : 0.f;
      float sc = QKV ? (col < 512 ? QSCALE : 1.f) : 1.f;
      #pragma unroll
      for (int r = 0; r < 4; ++r) {
        int rowg = m0 + wm * (BM / 2) + i * 16 + quad * 4 + r;
        float v = acc[i][j][r] * sc + bv;
        if (RELU) v = fmaxf(v, 0.f);
        if (OUTBF16) Cb[(size_t)rowg * N + col] = f2b(v);
        else Cf[(size_t)rowg * N + col] = v;
      }
    }
}

// ---------------------------------------------------------------------------
// N=256 GEMM — R8's exact proven version: BM=BN=32, BK=64, grid (8,128)
// = 1024 blocks (4/CU, cross-block latency hiding). Simple VGPR staging.
// ---------------------------------------------------------------------------
__global__ __launch_bounds__(256) void gemm_n256(
    const unsigned short* __restrict__ A, const unsigned short* __restrict__ Bt,
    const float* __restrict__ bias, const float* __restrict__ resid,
    float* __restrict__ Cf, int K)
{
  __shared__ __align__(16) unsigned short As[32][72];
  __shared__ __align__(16) unsigned short Bs[32][72];
  const int tid = threadIdx.x;
  const int wave = tid >> 6, ln = tid & 63;
  const int quad = ln >> 4, l16 = ln & 15;
  const int wm = wave >> 1, wn = wave & 1;
  const int m0 = blockIdx.y * 32, n0 = blockIdx.x * 32;
  const int srow = tid >> 3, scol = (tid & 7) * 8;

  floatx4 acc = {};

  for (int kb = 0; kb < K; kb += 64) {
    float4 ta = *(const float4*)(A + (size_t)(m0 + srow) * K + kb + scol);
    float4 tb = *(const float4*)(Bt + (size_t)(n0 + srow) * K + kb + scol);
    __syncthreads();
    *(float4*)&As[srow][scol] = ta;
    *(float4*)&Bs[srow][scol] = tb;
    __syncthreads();
    #pragma unroll
    for (int kc = 0; kc < 2; ++kc) {
      bf16x8 af = *(const bf16x8*)&As[wm * 16 + l16][kc * 32 + quad * 8];
      bf16x8 bf = *(const bf16x8*)&Bs[wn * 16 + l16][kc * 32 + quad * 8];
      acc = __builtin_amdgcn_mfma_f32_16x16x32_bf16(af, bf, acc, 0, 0, 0);
    }
  }

  const int col = n0 + wn * 16 + l16;
  const float bv = bias[col];
  #pragma unroll
  for (int r = 0; r < 4; ++r) {
    int rowg = m0 + wm * 16 + quad * 4 + r;
    Cf[(size_t)rowg * 256 + col] = acc[r] + bv + resid[(size_t)rowg * 256 + col];
  }
}

// ---------------------------------------------------------------------------
// MFMA flash attention (unchanged — verified)
// ---------------------------------------------------------------------------
__global__ __launch_bounds__(256) void attn_kernel(
    const unsigned short* __restrict__ qkv, const float* __restrict__ bias49,
    unsigned short* __restrict__ o)
{
  const int i0 = blockIdx.x * 64;
  const int bh = blockIdx.y;
  const int b = bh >> 4, hh = bh & 15;
  const int tid = threadIdx.x;
  const int wave = tid >> 6, ln = tid & 63;
  const int quad = ln >> 4, l16 = ln & 15;

  __shared__ __align__(16) unsigned short Kt[64][40];
  __shared__ __align__(16) unsigned short Vt[32][72];
  __shared__ __align__(16) unsigned short Pw[4][2][16][72];
  __shared__ float bsh[49];

  if (tid < 49) bsh[tid] = bias49[hh * 49 + tid];

  const unsigned short* qkvb = qkv + (size_t)b * Ln * 1536;

  const int qrow = i0 + wave * 16 + l16;
  const bf16x8 qf = *(const bf16x8*)(qkvb + (size_t)qrow * 1536 + hh * 32 + quad * 8);

  float m[4], l[4];
  #pragma unroll
  for (int r = 0; r < 4; ++r) { m[r] = -1e30f; l[r] = 0.f; }
  floatx4 acc_o[2] = {};

  const int krow = tid >> 2, kch = (tid & 3) * 8;
  const int vkey = tid & 63, vch = (tid >> 6) * 8;

  for (int jt = 0; jt < 8; ++jt) {
    const int j0 = jt * 64;
    __syncthreads();
    *(float4*)&Kt[krow][kch] =
        *(const float4*)(qkvb + (size_t)(j0 + krow) * 1536 + 512 + hh * 32 + kch);
    bf16x8 vv = *(const bf16x8*)(qkvb + (size_t)(j0 + vkey) * 1536 + 1024 + hh * 32 + vch);
    #pragma unroll
    for (int i = 0; i < 8; ++i) Vt[vch + i][vkey] = (unsigned short)vv[i];
    __syncthreads();

    floatx4 s4[4];
    #pragma unroll
    for (int t = 0; t < 4; ++t) {
      bf16x8 kf = *(const bf16x8*)&Kt[16 * t + l16][quad * 8];
      s4[t] = __builtin_amdgcn_mfma_f32_16x16x32_bf16(qf, kf, (floatx4){0.f, 0.f, 0.f, 0.f}, 0, 0, 0);
    }
    const int relmin = j0 - (i0 + 63), relmax = j0 + 63 - i0;
    if (relmin >= PMAX) {
      float bc = bsh[48];
      #pragma unroll
      for (int t = 0; t < 4; ++t)
        #pragma unroll
        for (int r = 0; r < 4; ++r) s4[t][r] += bc;
    } else if (relmax <= -PMAX) {
      float bc = bsh[0];
      #pragma unroll
      for (int t = 0; t < 4; ++t)
        #pragma unroll
        for (int r = 0; r < 4; ++r) s4[t][r] += bc;
    } else {
      const int base_rel = (j0 + l16) - (i0 + wave * 16 + quad * 4);
      #pragma unroll
      for (int t = 0; t < 4; ++t)
        #pragma unroll
        for (int r = 0; r < 4; ++r) {
          int rel = base_rel + 16 * t - r;
          rel = rel < -PMAX ? -PMAX : (rel > PMAX ? PMAX : rel);
          s4[t][r] += bsh[rel + PMAX];
        }
    }

    float mloc[4], alpha[4], psum[4];
    #pragma unroll
    for (int r = 0; r < 4; ++r) {
      mloc[r] = fmaxf(fmaxf(s4[0][r], s4[1][r]), fmaxf(s4[2][r], s4[3][r]));
      #pragma unroll
      for (int off = 1; off < 16; off <<= 1)
        mloc[r] = fmaxf(mloc[r], __shfl_xor(mloc[r], off, 64));
      float mnew = fmaxf(m[r], mloc[r]);
      alpha[r] = __expf(m[r] - mnew);
      m[r] = mnew;
      psum[r] = 0.f;
    }
    #pragma unroll
    for (int t = 0; t < 4; ++t)
      #pragma unroll
      for (int r = 0; r < 4; ++r) {
        float p = __expf(s4[t][r] - m[r]);
        s4[t][r] = p;
        psum[r] += p;
      }
    #pragma unroll
    for (int r = 0; r < 4; ++r) {
      #pragma unroll
      for (int off = 1; off < 16; off <<= 1)
        psum[r] += __shfl_xor(psum[r], off, 64);
      l[r] = l[r] * alpha[r] + psum[r];
      acc_o[0][r] *= alpha[r];
      acc_o[1][r] *= alpha[r];
    }

    #pragma unroll
    for (int t = 0; t < 4; ++t)
      #pragma unroll
      for (int r = 0; r < 4; ++r) {
        float p = s4[t][r];
        unsigned short hi = f2b(p);
        unsigned short lo = f2b(p - b2f(hi));
        Pw[wave][0][quad * 4 + r][16 * t + l16] = hi;
        Pw[wave][1][quad * 4 + r][16 * t + l16] = lo;
      }

    #pragma unroll
    for (int kh = 0; kh < 2; ++kh) {
      bf16x8 phi = *(const bf16x8*)&Pw[wave][0][l16][kh * 32 + quad * 8];
      bf16x8 plo = *(const bf16x8*)&Pw[wave][1][l16][kh * 32 + quad * 8];
      #pragma unroll
      for (int nt = 0; nt < 2; ++nt) {
        bf16x8 vf = *(const bf16x8*)&Vt[nt * 16 + l16][kh * 32 + quad * 8];
        acc_o[nt] = __builtin_amdgcn_mfma_f32_16x16x32_bf16(phi, vf, acc_o[nt], 0, 0, 0);
        acc_o[nt] = __builtin_amdgcn_mfma_f32_16x16x32_bf16(plo, vf, acc_o[nt], 0, 0, 0);
      }
    }
  }

  #pragma unroll
  for (int r = 0; r < 4; ++r) {
    float inv = 1.f / l[r];
    size_t rowg = (size_t)b * Ln + i0 + wave * 16 + quad * 4 + r;
    #pragma unroll
    for (int nt = 0; nt < 2; ++nt)
      o[rowg * 512 + hh * 32 + nt * 16 + l16] = f2b(acc_o[nt][r] * inv);
  }
}

// ---------------------------------------------------------------------------
// LayerNorm over E=256 — wave-per-row, ZERO barriers. 4 rows per block
// (grid 1024); each 64-lane wave owns one row: one float4/lane, sum+sumsq
// via 6 shfl_xor steps, vectorized stores. fp32 math (order differs from
// R8's tree; R5/R7 showed LN fp32-order perturbation leaves absmax intact).
// ---------------------------------------------------------------------------
__global__ __launch_bounds__(256) void ln_kernel(
    const float* __restrict__ xin, const float* __restrict__ g,
    const float* __restrict__ be, float* __restrict__ hout,
    unsigned short* __restrict__ bout, int bstride)
{
  const int w = threadIdx.x >> 6, lane = threadIdx.x & 63;
  const size_t row = (size_t)blockIdx.x * 4 + w;
  const int c0 = lane * 4;
  float4 v = *(const float4*)(xin + row * E + c0);
  float s = v.x + v.y + v.z + v.w;
  float s2 = v.x * v.x + v.y * v.y + v.z * v.z + v.w * v.w;
  #pragma unroll
  for (int off = 1; off < 64; off <<= 1) {
    s += __shfl_xor(s, off, 64);
    s2 += __shfl_xor(s2, off, 64);
  }
  const float mean = s * (1.f / E);
  const float rstd = rsqrtf(s2 * (1.f / E) - mean * mean + 1e-5f);
  const float4 gv = *(const float4*)(g + c0);
  const float4 bv = *(const float4*)(be + c0);
  float4 y;
  y.x = (v.x - mean) * rstd * gv.x + bv.x;
  y.y = (v.y - mean) * rstd * gv.y + bv.y;
  y.z = (v.z - mean) * rstd * gv.z + bv.z;
  y.w = (v.w - mean) * rstd * gv.w + bv.w;
  *(float4*)(hout + row * E + c0) = y;
  ushort4 yb;
  yb.x = f2b(y.x); yb.y = f2b(y.y); yb.z = f2b(y.z); yb.w = f2b(y.w);
  *(ushort4*)(bout + row * (size_t)bstride + c0) = yb;
}

// ---------------------------------------------------------------------------
// fp32 tiled GEMM: C = act(A@B + bias), optional bf16 mirror (embed2 / head)
// ---------------------------------------------------------------------------
template<bool RELU, bool BIAS, bool MIRROR>
__global__ __launch_bounds__(256) void gemm64f(
    const float* __restrict__ A, const float* __restrict__ B,
    const float* __restrict__ bias, float* __restrict__ C,
    unsigned short* __restrict__ mir, int N, int K)
{
  __shared__ __align__(16) float As[16][64];
  __shared__ __align__(16) float Bss[16][68];
  const int tid = threadIdx.x;
  const int tx = tid & 15, ty = tid >> 4;
  const int m0 = blockIdx.y * 64, n0 = blockIdx.x * 64;
  const int arow = tid >> 2, acol = (tid & 3) * 4;
  const int brow = tid >> 6, bcol = tid & 63;
  float acc[4][4] = {};
  for (int kb = 0; kb < K; kb += 16) {
    __syncthreads();
    float4 av = *(const float4*)(A + (size_t)(m0 + arow) * K + kb + acol);
    As[acol + 0][arow] = av.x; As[acol + 1][arow] = av.y;
    As[acol + 2][arow] = av.z; As[acol + 3][arow] = av.w;
    #pragma unroll
    for (int kk = 0; kk < 4; ++kk)
      Bss[brow + kk * 4][bcol] = B[(size_t)(kb + brow + kk * 4) * N + n0 + bcol];
    __syncthreads();
    #pragma unroll
    for (int k = 0; k < 16; ++k) {
      float4 a = *(const float4*)&As[k][4 * ty];
      float4 b = *(const float4*)&Bss[k][4 * tx];
      float av4[4] = {a.x, a.y, a.z, a.w};
      float bv4[4] = {b.x, b.y, b.z, b.w};
      #pragma unroll
      for (int ii = 0; ii < 4; ++ii)
        #pragma unroll
        for (int jj = 0; jj < 4; ++jj)
          acc[ii][jj] += av4[ii] * bv4[jj];
    }
  }
  #pragma unroll
  for (int ii = 0; ii < 4; ++ii) {
    size_t row = (size_t)m0 + 4 * ty + ii;
    int col = n0 + 4 * tx;
    float4 vv;
    vv.x = acc[ii][0]; vv.y = acc[ii][1]; vv.z = acc[ii][2]; vv.w = acc[ii][3];
    if (BIAS) {
      float4 bb = *(const float4*)(bias + col);
      vv.x += bb.x; vv.y += bb.y; vv.z += bb.z; vv.w += bb.w;
    }
    if (RELU) {
      vv.x = fmaxf(vv.x, 0.f); vv.y = fmaxf(vv.y, 0.f);
      vv.z = fmaxf(vv.z, 0.f); vv.w = fmaxf(vv.w, 0.f);
    }
    *(float4*)(C + row * N + col) = vv;
    if (MIRROR) {
      ushort4 mv;
      mv.x = f2b(vv.x); mv.y = f2b(vv.y); mv.z = f2b(vv.z); mv.w = f2b(vv.w);
      *(ushort4*)(mir + row * N + col) = mv;
    }
  }
}

__global__ __launch_bounds__(256) void final_r_kernel(
    const float* __restrict__ t1, const float* __restrict__ w2,
    const float* __restrict__ b2, float* __restrict__ r)
{
  int row = blockIdx.x, t = threadIdx.x;
  float xv = t1[(size_t)row * E + t];
  float p0 = xv * w2[t * 3 + 0];
  float p1 = xv * w2[t * 3 + 1];
  float p2 = xv * w2[t * 3 + 2];
  #pragma unroll
  for (int off = 32; off > 0; off >>= 1) {
    p0 += __shfl_down(p0, off, 64);
    p1 += __shfl_down(p1, off, 64);
    p2 += __shfl_down(p2, off, 64);
  }
  __shared__ float red[4][3];
  if ((t & 63) == 0) { int w = t >> 6; red[w][0] = p0; red[w][1] = p1; red[w][2] = p2; }
  __syncthreads();
  if (t < 3)
    r[(size_t)row * 3 + t] = red[0][t] + red[1][t] + red[2][t] + red[3][t] + b2[t];
}

__global__ __launch_bounds__(512) void dist_kernel(
    const float* __restrict__ r, float* __restrict__ out)
{
  int bi = blockIdx.x;
  int j = threadIdx.x;
  int b = bi >> 9;
  float x0 = r[(size_t)bi * 3 + 0];
  float y0 = r[(size_t)bi * 3 + 1];
  float z0 = r[(size_t)bi * 3 + 2];
  const float* rj = r + ((size_t)b * Ln + j) * 3;
  float dx = rj[0] - x0, dy = rj[1] - y0, dz = rj[2] - z0;
  out[(size_t)bi * Ln + j] = sqrtf(dx * dx + dy * dy + dz * dz + 1e-12f);
}

// ---------------------------------------------------------------------------
extern "C" void kernel_launch(void* const* d_in, const int* in_sizes, int n_in,
                              void* d_out, int out_size, void* d_ws, size_t ws_size,
                              hipStream_t stream)
{
  const float* z     = (const float*)d_in[0];
  const float* x     = (const float*)d_in[1];
  const float* pos   = (const float*)d_in[2];
  const float* aa    = (const float*)d_in[3];
  const float* ex_w1 = (const float*)d_in[4];
  const float* ex_b1 = (const float*)d_in[5];
  const float* ex_w2 = (const float*)d_in[6];
  const float* ex_b2 = (const float*)d_in[7];
  const float* Wq    = (const float*)d_in[8];
  const float* Wk    = (const float*)d_in[9];
  const float* Wv    = (const float*)d_in[10];
  const float* Wo    = (const float*)d_in[11];
  const float* bo    = (const float*)d_in[12];
  const float* W2d   = (const float*)d_in[13];
  const float* b2d   = (const float*)d_in[14];
  const float* W1    = (const float*)d_in[15];
  const float* b1    = (const float*)d_in[16];
  const float* W2    = (const float*)d_in[17];
  const float* b2    = (const float*)d_in[18];
  const float* g1    = (const float*)d_in[19];
  const float* be1   = (const float*)d_in[20];
  const float* g2    = (const float*)d_in[21];
  const float* be2   = (const float*)d_in[22];
  const float* m3w1  = (const float*)d_in[23];
  const float* m3b1  = (const float*)d_in[24];
  const float* m3w2  = (const float*)d_in[25];
  const float* m3b2  = (const float*)d_in[26];

  float* ws     = (float*)d_ws;
  float* h      = ws;                          // 4096*256
  float* t0     = h + (size_t)ROWS * E;        // 4096*256 (embed hidden / tmp)
  float* r      = t0 + (size_t)ROWS * E;       // 4096*3
  float* bias49 = r + (size_t)ROWS * 3;        // 8*16*49
  unsigned short* us = (unsigned short*)(bias49 + NL * NH * 49);
  unsigned short* hb   = us;                              // 4096*256
  unsigned short* umb  = hb  + (size_t)ROWS * E;          // 4096*288
  unsigned short* qkvb = umb + (size_t)ROWS * (E + E1D);  // 4096*1536
  unsigned short* ob   = qkvb + (size_t)ROWS * 3 * DM;    // 4096*512
  unsigned short* t1b  = ob  + (size_t)ROWS * DM;         // 4096*1024
  unsigned short* qkvT = t1b + (size_t)ROWS * FF;         // 8*1536*256
  unsigned short* WoT  = qkvT + (size_t)NL * 3 * DM * E;  // 8*256*512
  unsigned short* W1T  = WoT  + (size_t)NL * E * DM;      // 8*1024*288
  unsigned short* W2T  = W1T  + (size_t)NL * FF * (E+E1D);// 8*256*1024
  float* tmp = t0;            // layer-loop scratch aliases t0
  float* t1f = (float*)t1b;   // head scratch aliases t1b

  // ---- weight transpose+convert (4 launches) ----
  transpose_qkv<<<dim3(DM/32, E/32, 3*NL), 256, 0, stream>>>(Wq, Wk, Wv, qkvT);
  transpose_bf16<<<dim3(E/32, DM/32, NL), 256, 0, stream>>>(
      Wo, WoT, DM, E, (size_t)DM * E, (size_t)DM * E);
  transpose_bf16<<<dim3(FF/32, (E+E1D)/32, NL), 256, 0, stream>>>(
      W1, W1T, E + E1D, FF, (size_t)(E+E1D) * FF, (size_t)(E+E1D) * FF);
  transpose_bf16<<<dim3(E/32, FF/32, NL), 256, 0, stream>>>(
      W2, W2T, FF, E, (size_t)FF * E, (size_t)FF * E);

  embed1_kernel<<<ROWS, 256, 0, stream>>>(z, x, aa, ex_w1, ex_b1, t0, umb);
  gemm64f<false,true,true><<<dim3(E/64, ROWS/64), 256, 0, stream>>>(
      t0, ex_w2, ex_b2, h, hb, E, E);
  bias_kernel<<<NL, 256, 0, stream>>>(pos, W2d, b2d, bias49);

  for (int i = 0; i < NL; ++i) {
    // fused QKV: N=1536, 128x128 tiles, q-scale on cols<512, bf16 out
    gemm_mfma<128,128,false,false,true,true><<<dim3(12, 32), 256, 0, stream>>>(
        hb, qkvT + (size_t)i * 3 * DM * E, nullptr, nullptr, qkvb, 3 * DM, E);
    attn_kernel<<<dim3(Ln/64, Bn*NH), 256, 0, stream>>>(
        qkvb, bias49 + (size_t)i * NH * 49, ob);
    // Wo + bias + resid(h) -> tmp fp32  (1024 blocks, 4/CU — R8 proven)
    gemm_n256<<<dim3(E/32, ROWS/32), 256, 0, stream>>>(
        ob, WoT + (size_t)i * DM * E, bo + (size_t)i * E, h, tmp, DM);
    ln_kernel<<<ROWS/4, 256, 0, stream>>>(tmp, g1 + (size_t)i * E, be1 + (size_t)i * E, h, umb, E + E1D);
    // FF1 + bias + relu -> bf16 t1b
    gemm_mfma<128,128,true,true,true,false><<<dim3(FF/128, ROWS/128), 256, 0, stream>>>(
        umb, W1T + (size_t)i * FF * (E+E1D), b1 + (size_t)i * FF, nullptr, t1b, FF, E + E1D);
    // FF2 + bias + resid(h) -> tmp fp32  (1024 blocks, 4/CU — R8 proven)
    gemm_n256<<<dim3(E/32, ROWS/32), 256, 0, stream>>>(
        t1b, W2T + (size_t)i * E * FF, b2 + (size_t)i * E, h, tmp, FF);
    ln_kernel<<<ROWS/4, 256, 0, stream>>>(tmp, g2 + (size_t)i * E, be2 + (size_t)i * E, h, hb, E);
  }

  // fp32 head
  gemm64f<true,true,false><<<dim3(E/64, ROWS/64), 256, 0, stream>>>(
      h, m3w1, m3b1, t1f, nullptr, E, E);
  final_r_kernel<<<ROWS, 256, 0, stream>>>(t1f, m3w2, m3b2, r);
  dist_kernel<<<ROWS, 512, 0, stream>>>(r, (float*)d_out);
}

// Round 12
// 859.168 us; speedup vs baseline: 1.1524x; 1.0192x over previous
//
#include <hip/hip_runtime.h>
#include <math.h>

constexpr int Bn = 8, NZ = 16, Ln = 512;
constexpr int E = 256, DM = 512, NH = 16, HD = 32;
constexpr int FF = 1024, NL = 8, E1D = 32, PDIM = 64, PMAX = 24;
constexpr int ROWS = Bn * Ln;                       // 4096
constexpr float QSCALE = 0.04419417382415922f;      // 1/sqrt(512)

typedef __attribute__((ext_vector_type(8))) short bf16x8;
typedef __attribute__((ext_vector_type(4))) float floatx4;

__device__ inline unsigned short f2b(float f) {
  union { float f; unsigned u; } v; v.f = f;
  unsigned r = (v.u + 0x7FFF + ((v.u >> 16) & 1)) >> 16;
  return (unsigned short)r;
}
__device__ inline float b2f(unsigned short u) {
  union { unsigned u; float f; } v; v.u = ((unsigned)u) << 16; return v.f;
}

// ---------------------------------------------------------------------------
// batched Wq/Wk/Wv fp32 [l][E][DM] -> bf16 qkvT [l][3*DM][E]
// ---------------------------------------------------------------------------
__global__ __launch_bounds__(256) void transpose_qkv(
    const float* __restrict__ Wq, const float* __restrict__ Wk,
    const float* __restrict__ Wv, unsigned short* __restrict__ qkvT)
{
  __shared__ float t[32][33];
  int zb = blockIdx.z;
  int which = zb / NL, l = zb % NL;
  const float* s = (which == 0 ? Wq : which == 1 ? Wk : Wv) + (size_t)l * E * DM;
  unsigned short* d = qkvT + (size_t)l * 3 * DM * E + (size_t)which * DM * E;
  int c0 = blockIdx.x * 32, r0 = blockIdx.y * 32;
  int tx = threadIdx.x & 31, ty = threadIdx.x >> 5;
  #pragma unroll
  for (int i = 0; i < 4; ++i)
    t[ty + i * 8][tx] = s[(size_t)(r0 + ty + i * 8) * DM + c0 + tx];
  __syncthreads();
  #pragma unroll
  for (int i = 0; i < 4; ++i)
    d[(size_t)(c0 + ty + i * 8) * E + r0 + tx] = f2b(t[tx][ty + i * 8]);
}

// ---------------------------------------------------------------------------
// generic fp32 [l][R][C] -> bf16 [l][C][R]
// ---------------------------------------------------------------------------
__global__ __launch_bounds__(256) void transpose_bf16(
    const float* __restrict__ src, unsigned short* __restrict__ dst,
    int R, int C, size_t sls, size_t dls)
{
  __shared__ float t[32][33];
  int l = blockIdx.z;
  int c0 = blockIdx.x * 32, r0 = blockIdx.y * 32;
  int tx = threadIdx.x & 31, ty = threadIdx.x >> 5;
  const float* s = src + (size_t)l * sls;
  unsigned short* d = dst + (size_t)l * dls;
  #pragma unroll
  for (int i = 0; i < 4; ++i)
    t[ty + i * 8][tx] = s[(size_t)(r0 + ty + i * 8) * C + c0 + tx];
  __syncthreads();
  #pragma unroll
  for (int i = 0; i < 4; ++i)
    d[(size_t)(c0 + ty + i * 8) * R + r0 + tx] = f2b(t[tx][ty + i * 8]);
}

// ---------------------------------------------------------------------------
// embed stage 1: t0 = relu(z^T @ ex_w1 + b1) fp32; e_aa gather into umb
// ---------------------------------------------------------------------------
__global__ __launch_bounds__(256) void embed1_kernel(
    const float* __restrict__ z, const float* __restrict__ x,
    const float* __restrict__ aa,
    const float* __restrict__ w1, const float* __restrict__ b1,
    float* __restrict__ t0, unsigned short* __restrict__ umb)
{
  int row = blockIdx.x;
  int b = row >> 9, l = row & (Ln - 1);
  int t = threadIdx.x;
  __shared__ float zs[NZ];
  __shared__ int am_s;
  if (t < NZ) zs[t] = z[((size_t)b * NZ + t) * Ln + l];
  if (t == 0) {
    const float* xp = x + (size_t)b * 20 * Ln + l;
    int am = 0; float bv = xp[0];
    for (int c = 1; c < 20; ++c) { float vv = xp[(size_t)c * Ln]; if (vv > bv) { bv = vv; am = c; } }
    am_s = am;
  }
  __syncthreads();
  float a1 = b1[t];
  #pragma unroll
  for (int nz = 0; nz < NZ; ++nz) a1 += zs[nz] * w1[nz * E + t];
  t0[(size_t)row * E + t] = fmaxf(a1, 0.f);
  if (t < E1D) umb[(size_t)row * (E + E1D) + E + t] = f2b(aa[am_s * E1D + t]);
}

// ---------------------------------------------------------------------------
// pairwise-bias collapse: 49 bins per (layer, head)
// ---------------------------------------------------------------------------
__global__ __launch_bounds__(256) void bias_kernel(
    const float* __restrict__ pos, const float* __restrict__ W2d,
    const float* __restrict__ b2d, float* __restrict__ bias49)
{
  int layer = blockIdx.x;
  for (int idx = threadIdx.x; idx < NH * 49; idx += 256) {
    int hh = idx / 49, bin = idx % 49;
    float acc = b2d[layer * NH + hh];
    for (int p = 0; p < PDIM; ++p)
      acc += pos[bin * PDIM + p] * W2d[((size_t)layer * PDIM + p) * NH + hh];
    bias49[(size_t)layer * NH * 49 + hh * 49 + bin] = acc;
  }
}

// ---------------------------------------------------------------------------
// bf16 MFMA GEMM, BK=32, plain staging (R8-proven body).
// R12: QKV at 64x128 (768 blocks, 3/CU), FF1 at 64x64 (1024 blocks, 4/CU)
// — fixes the 1 block/CU occupancy hole that R4-R7 taught us about.
// Ascending-k accumulation: outputs bitwise identical to R11.
// ---------------------------------------------------------------------------
template<int BM, int BN, bool BIAS, bool RELU, bool OUTBF16, bool QKV>
__global__ __launch_bounds__(256) void gemm_mfma(
    const unsigned short* __restrict__ A, const unsigned short* __restrict__ Bt,
    const float* __restrict__ bias,
    float* __restrict__ Cf, unsigned short* __restrict__ Cb, int N, int K)
{
  constexpr int MT = BM / 32, NT = BN / 32;
  __shared__ __align__(16) unsigned short As[BM][40];
  __shared__ __align__(16) unsigned short Bs[BN][40];
  const int tid = threadIdx.x;
  const int wave = tid >> 6, ln = tid & 63;
  const int quad = ln >> 4, l16 = ln & 15;
  const int wm = wave >> 1, wn = wave & 1;
  const int m0 = blockIdx.y * BM, n0 = blockIdx.x * BN;

  floatx4 acc[MT][NT] = {};

  for (int kb = 0; kb < K; kb += 32) {
    __syncthreads();
    #pragma unroll
    for (int it = 0; it < BM / 64; ++it) {
      int c = tid + it * 256;
      int row = c >> 2, cc = (c & 3) * 8;
      *(float4*)&As[row][cc] = *(const float4*)(A + (size_t)(m0 + row) * K + kb + cc);
    }
    #pragma unroll
    for (int it = 0; it < BN / 64; ++it) {
      int c = tid + it * 256;
      int row = c >> 2, cc = (c & 3) * 8;
      *(float4*)&Bs[row][cc] = *(const float4*)(Bt + (size_t)(n0 + row) * K + kb + cc);
    }
    __syncthreads();
    bf16x8 af[MT], bfr[NT];
    #pragma unroll
    for (int i = 0; i < MT; ++i)
      af[i] = *(const bf16x8*)&As[wm * (BM / 2) + i * 16 + l16][quad * 8];
    #pragma unroll
    for (int j = 0; j < NT; ++j)
      bfr[j] = *(const bf16x8*)&Bs[wn * (BN / 2) + j * 16 + l16][quad * 8];
    #pragma unroll
    for (int i = 0; i < MT; ++i)
      #pragma unroll
      for (int j = 0; j < NT; ++j)
        acc[i][j] = __builtin_amdgcn_mfma_f32_16x16x32_bf16(af[i], bfr[j], acc[i][j], 0, 0, 0);
  }

  #pragma unroll
  for (int i = 0; i < MT; ++i)
    #pragma unroll
    for (int j = 0; j < NT; ++j) {
      int col = n0 + wn * (BN / 2) + j * 16 + l16;
      float bv = BIAS ? bias[col] : 0.f;
      float sc = QKV ? (col < 512 ? QSCALE : 1.f) : 1.f;
      #pragma unroll
      for (int r = 0; r < 4; ++r) {
        int rowg = m0 + wm * (BM / 2) + i * 16 + quad * 4 + r;
        float v = acc[i][j][r] * sc + bv;
        if (RELU) v = fmaxf(v, 0.f);
        if (OUTBF16) Cb[(size_t)rowg * N + col] = f2b(v);
        else Cf[(size_t)rowg * N + col] = v;
      }
    }
}

// ---------------------------------------------------------------------------
// N=256 GEMM — R8's exact proven version: BM=BN=32, BK=64, grid (8,128)
// = 1024 blocks (4/CU, cross-block latency hiding). Simple VGPR staging.
// ---------------------------------------------------------------------------
__global__ __launch_bounds__(256) void gemm_n256(
    const unsigned short* __restrict__ A, const unsigned short* __restrict__ Bt,
    const float* __restrict__ bias, const float* __restrict__ resid,
    float* __restrict__ Cf, int K)
{
  __shared__ __align__(16) unsigned short As[32][72];
  __shared__ __align__(16) unsigned short Bs[32][72];
  const int tid = threadIdx.x;
  const int wave = tid >> 6, ln = tid & 63;
  const int quad = ln >> 4, l16 = ln & 15;
  const int wm = wave >> 1, wn = wave & 1;
  const int m0 = blockIdx.y * 32, n0 = blockIdx.x * 32;
  const int srow = tid >> 3, scol = (tid & 7) * 8;

  floatx4 acc = {};

  for (int kb = 0; kb < K; kb += 64) {
    float4 ta = *(const float4*)(A + (size_t)(m0 + srow) * K + kb + scol);
    float4 tb = *(const float4*)(Bt + (size_t)(n0 + srow) * K + kb + scol);
    __syncthreads();
    *(float4*)&As[srow][scol] = ta;
    *(float4*)&Bs[srow][scol] = tb;
    __syncthreads();
    #pragma unroll
    for (int kc = 0; kc < 2; ++kc) {
      bf16x8 af = *(const bf16x8*)&As[wm * 16 + l16][kc * 32 + quad * 8];
      bf16x8 bf = *(const bf16x8*)&Bs[wn * 16 + l16][kc * 32 + quad * 8];
      acc = __builtin_amdgcn_mfma_f32_16x16x32_bf16(af, bf, acc, 0, 0, 0);
    }
  }

  const int col = n0 + wn * 16 + l16;
  const float bv = bias[col];
  #pragma unroll
  for (int r = 0; r < 4; ++r) {
    int rowg = m0 + wm * 16 + quad * 4 + r;
    Cf[(size_t)rowg * 256 + col] = acc[r] + bv + resid[(size_t)rowg * 256 + col];
  }
}

// ---------------------------------------------------------------------------
// MFMA flash attention (unchanged — verified)
// ---------------------------------------------------------------------------
__global__ __launch_bounds__(256) void attn_kernel(
    const unsigned short* __restrict__ qkv, const float* __restrict__ bias49,
    unsigned short* __restrict__ o)
{
  const int i0 = blockIdx.x * 64;
  const int bh = blockIdx.y;
  const int b = bh >> 4, hh = bh & 15;
  const int tid = threadIdx.x;
  const int wave = tid >> 6, ln = tid & 63;
  const int quad = ln >> 4, l16 = ln & 15;

  __shared__ __align__(16) unsigned short Kt[64][40];
  __shared__ __align__(16) unsigned short Vt[32][72];
  __shared__ __align__(16) unsigned short Pw[4][2][16][72];
  __shared__ float bsh[49];

  if (tid < 49) bsh[tid] = bias49[hh * 49 + tid];

  const unsigned short* qkvb = qkv + (size_t)b * Ln * 1536;

  const int qrow = i0 + wave * 16 + l16;
  const bf16x8 qf = *(const bf16x8*)(qkvb + (size_t)qrow * 1536 + hh * 32 + quad * 8);

  float m[4], l[4];
  #pragma unroll
  for (int r = 0; r < 4; ++r) { m[r] = -1e30f; l[r] = 0.f; }
  floatx4 acc_o[2] = {};

  const int krow = tid >> 2, kch = (tid & 3) * 8;
  const int vkey = tid & 63, vch = (tid >> 6) * 8;

  for (int jt = 0; jt < 8; ++jt) {
    const int j0 = jt * 64;
    __syncthreads();
    *(float4*)&Kt[krow][kch] =
        *(const float4*)(qkvb + (size_t)(j0 + krow) * 1536 + 512 + hh * 32 + kch);
    bf16x8 vv = *(const bf16x8*)(qkvb + (size_t)(j0 + vkey) * 1536 + 1024 + hh * 32 + vch);
    #pragma unroll
    for (int i = 0; i < 8; ++i) Vt[vch + i][vkey] = (unsigned short)vv[i];
    __syncthreads();

    floatx4 s4[4];
    #pragma unroll
    for (int t = 0; t < 4; ++t) {
      bf16x8 kf = *(const bf16x8*)&Kt[16 * t + l16][quad * 8];
      s4[t] = __builtin_amdgcn_mfma_f32_16x16x32_bf16(qf, kf, (floatx4){0.f, 0.f, 0.f, 0.f}, 0, 0, 0);
    }
    const int relmin = j0 - (i0 + 63), relmax = j0 + 63 - i0;
    if (relmin >= PMAX) {
      float bc = bsh[48];
      #pragma unroll
      for (int t = 0; t < 4; ++t)
        #pragma unroll
        for (int r = 0; r < 4; ++r) s4[t][r] += bc;
    } else if (relmax <= -PMAX) {
      float bc = bsh[0];
      #pragma unroll
      for (int t = 0; t < 4; ++t)
        #pragma unroll
        for (int r = 0; r < 4; ++r) s4[t][r] += bc;
    } else {
      const int base_rel = (j0 + l16) - (i0 + wave * 16 + quad * 4);
      #pragma unroll
      for (int t = 0; t < 4; ++t)
        #pragma unroll
        for (int r = 0; r < 4; ++r) {
          int rel = base_rel + 16 * t - r;
          rel = rel < -PMAX ? -PMAX : (rel > PMAX ? PMAX : rel);
          s4[t][r] += bsh[rel + PMAX];
        }
    }

    float mloc[4], alpha[4], psum[4];
    #pragma unroll
    for (int r = 0; r < 4; ++r) {
      mloc[r] = fmaxf(fmaxf(s4[0][r], s4[1][r]), fmaxf(s4[2][r], s4[3][r]));
      #pragma unroll
      for (int off = 1; off < 16; off <<= 1)
        mloc[r] = fmaxf(mloc[r], __shfl_xor(mloc[r], off, 64));
      float mnew = fmaxf(m[r], mloc[r]);
      alpha[r] = __expf(m[r] - mnew);
      m[r] = mnew;
      psum[r] = 0.f;
    }
    #pragma unroll
    for (int t = 0; t < 4; ++t)
      #pragma unroll
      for (int r = 0; r < 4; ++r) {
        float p = __expf(s4[t][r] - m[r]);
        s4[t][r] = p;
        psum[r] += p;
      }
    #pragma unroll
    for (int r = 0; r < 4; ++r) {
      #pragma unroll
      for (int off = 1; off < 16; off <<= 1)
        psum[r] += __shfl_xor(psum[r], off, 64);
      l[r] = l[r] * alpha[r] + psum[r];
      acc_o[0][r] *= alpha[r];
      acc_o[1][r] *= alpha[r];
    }

    #pragma unroll
    for (int t = 0; t < 4; ++t)
      #pragma unroll
      for (int r = 0; r < 4; ++r) {
        float p = s4[t][r];
        unsigned short hi = f2b(p);
        unsigned short lo = f2b(p - b2f(hi));
        Pw[wave][0][quad * 4 + r][16 * t + l16] = hi;
        Pw[wave][1][quad * 4 + r][16 * t + l16] = lo;
      }

    #pragma unroll
    for (int kh = 0; kh < 2; ++kh) {
      bf16x8 phi = *(const bf16x8*)&Pw[wave][0][l16][kh * 32 + quad * 8];
      bf16x8 plo = *(const bf16x8*)&Pw[wave][1][l16][kh * 32 + quad * 8];
      #pragma unroll
      for (int nt = 0; nt < 2; ++nt) {
        bf16x8 vf = *(const bf16x8*)&Vt[nt * 16 + l16][kh * 32 + quad * 8];
        acc_o[nt] = __builtin_amdgcn_mfma_f32_16x16x32_bf16(phi, vf, acc_o[nt], 0, 0, 0);
        acc_o[nt] = __builtin_amdgcn_mfma_f32_16x16x32_bf16(plo, vf, acc_o[nt], 0, 0, 0);
      }
    }
  }

  #pragma unroll
  for (int r = 0; r < 4; ++r) {
    float inv = 1.f / l[r];
    size_t rowg = (size_t)b * Ln + i0 + wave * 16 + quad * 4 + r;
    #pragma unroll
    for (int nt = 0; nt < 2; ++nt)
      o[rowg * 512 + hh * 32 + nt * 16 + l16] = f2b(acc_o[nt][r] * inv);
  }
}

// ---------------------------------------------------------------------------
// LayerNorm over E=256 — wave-per-row, zero barriers (R11-proven).
// ---------------------------------------------------------------------------
__global__ __launch_bounds__(256) void ln_kernel(
    const float* __restrict__ xin, const float* __restrict__ g,
    const float* __restrict__ be, float* __restrict__ hout,
    unsigned short* __restrict__ bout, int bstride)
{
  const int w = threadIdx.x >> 6, lane = threadIdx.x & 63;
  const size_t row = (size_t)blockIdx.x * 4 + w;
  const int c0 = lane * 4;
  float4 v = *(const float4*)(xin + row * E + c0);
  float s = v.x + v.y + v.z + v.w;
  float s2 = v.x * v.x + v.y * v.y + v.z * v.z + v.w * v.w;
  #pragma unroll
  for (int off = 1; off < 64; off <<= 1) {
    s += __shfl_xor(s, off, 64);
    s2 += __shfl_xor(s2, off, 64);
  }
  const float mean = s * (1.f / E);
  const float rstd = rsqrtf(s2 * (1.f / E) - mean * mean + 1e-5f);
  const float4 gv = *(const float4*)(g + c0);
  const float4 bv = *(const float4*)(be + c0);
  float4 y;
  y.x = (v.x - mean) * rstd * gv.x + bv.x;
  y.y = (v.y - mean) * rstd * gv.y + bv.y;
  y.z = (v.z - mean) * rstd * gv.z + bv.z;
  y.w = (v.w - mean) * rstd * gv.w + bv.w;
  *(float4*)(hout + row * E + c0) = y;
  ushort4 yb;
  yb.x = f2b(y.x); yb.y = f2b(y.y); yb.z = f2b(y.z); yb.w = f2b(y.w);
  *(ushort4*)(bout + row * (size_t)bstride + c0) = yb;
}

// ---------------------------------------------------------------------------
// fp32 tiled GEMM: C = act(A@B + bias), optional bf16 mirror (embed2 / head)
// ---------------------------------------------------------------------------
template<bool RELU, bool BIAS, bool MIRROR>
__global__ __launch_bounds__(256) void gemm64f(
    const float* __restrict__ A, const float* __restrict__ B,
    const float* __restrict__ bias, float* __restrict__ C,
    unsigned short* __restrict__ mir, int N, int K)
{
  __shared__ __align__(16) float As[16][64];
  __shared__ __align__(16) float Bss[16][68];
  const int tid = threadIdx.x;
  const int tx = tid & 15, ty = tid >> 4;
  const int m0 = blockIdx.y * 64, n0 = blockIdx.x * 64;
  const int arow = tid >> 2, acol = (tid & 3) * 4;
  const int brow = tid >> 6, bcol = tid & 63;
  float acc[4][4] = {};
  for (int kb = 0; kb < K; kb += 16) {
    __syncthreads();
    float4 av = *(const float4*)(A + (size_t)(m0 + arow) * K + kb + acol);
    As[acol + 0][arow] = av.x; As[acol + 1][arow] = av.y;
    As[acol + 2][arow] = av.z; As[acol + 3][arow] = av.w;
    #pragma unroll
    for (int kk = 0; kk < 4; ++kk)
      Bss[brow + kk * 4][bcol] = B[(size_t)(kb + brow + kk * 4) * N + n0 + bcol];
    __syncthreads();
    #pragma unroll
    for (int k = 0; k < 16; ++k) {
      float4 a = *(const float4*)&As[k][4 * ty];
      float4 b = *(const float4*)&Bss[k][4 * tx];
      float av4[4] = {a.x, a.y, a.z, a.w};
      float bv4[4] = {b.x, b.y, b.z, b.w};
      #pragma unroll
      for (int ii = 0; ii < 4; ++ii)
        #pragma unroll
        for (int jj = 0; jj < 4; ++jj)
          acc[ii][jj] += av4[ii] * bv4[jj];
    }
  }
  #pragma unroll
  for (int ii = 0; ii < 4; ++ii) {
    size_t row = (size_t)m0 + 4 * ty + ii;
    int col = n0 + 4 * tx;
    float4 vv;
    vv.x = acc[ii][0]; vv.y = acc[ii][1]; vv.z = acc[ii][2]; vv.w = acc[ii][3];
    if (BIAS) {
      float4 bb = *(const float4*)(bias + col);
      vv.x += bb.x; vv.y += bb.y; vv.z += bb.z; vv.w += bb.w;
    }
    if (RELU) {
      vv.x = fmaxf(vv.x, 0.f); vv.y = fmaxf(vv.y, 0.f);
      vv.z = fmaxf(vv.z, 0.f); vv.w = fmaxf(vv.w, 0.f);
    }
    *(float4*)(C + row * N + col) = vv;
    if (MIRROR) {
      ushort4 mv;
      mv.x = f2b(vv.x); mv.y = f2b(vv.y); mv.z = f2b(vv.z); mv.w = f2b(vv.w);
      *(ushort4*)(mir + row * N + col) = mv;
    }
  }
}

__global__ __launch_bounds__(256) void final_r_kernel(
    const float* __restrict__ t1, const float* __restrict__ w2,
    const float* __restrict__ b2, float* __restrict__ r)
{
  int row = blockIdx.x, t = threadIdx.x;
  float xv = t1[(size_t)row * E + t];
  float p0 = xv * w2[t * 3 + 0];
  float p1 = xv * w2[t * 3 + 1];
  float p2 = xv * w2[t * 3 + 2];
  #pragma unroll
  for (int off = 32; off > 0; off >>= 1) {
    p0 += __shfl_down(p0, off, 64);
    p1 += __shfl_down(p1, off, 64);
    p2 += __shfl_down(p2, off, 64);
  }
  __shared__ float red[4][3];
  if ((t & 63) == 0) { int w = t >> 6; red[w][0] = p0; red[w][1] = p1; red[w][2] = p2; }
  __syncthreads();
  if (t < 3)
    r[(size_t)row * 3 + t] = red[0][t] + red[1][t] + red[2][t] + red[3][t] + b2[t];
}

__global__ __launch_bounds__(512) void dist_kernel(
    const float* __restrict__ r, float* __restrict__ out)
{
  int bi = blockIdx.x;
  int j = threadIdx.x;
  int b = bi >> 9;
  float x0 = r[(size_t)bi * 3 + 0];
  float y0 = r[(size_t)bi * 3 + 1];
  float z0 = r[(size_t)bi * 3 + 2];
  const float* rj = r + ((size_t)b * Ln + j) * 3;
  float dx = rj[0] - x0, dy = rj[1] - y0, dz = rj[2] - z0;
  out[(size_t)bi * Ln + j] = sqrtf(dx * dx + dy * dy + dz * dz + 1e-12f);
}

// ---------------------------------------------------------------------------
extern "C" void kernel_launch(void* const* d_in, const int* in_sizes, int n_in,
                              void* d_out, int out_size, void* d_ws, size_t ws_size,
                              hipStream_t stream)
{
  const float* z     = (const float*)d_in[0];
  const float* x     = (const float*)d_in[1];
  const float* pos   = (const float*)d_in[2];
  const float* aa    = (const float*)d_in[3];
  const float* ex_w1 = (const float*)d_in[4];
  const float* ex_b1 = (const float*)d_in[5];
  const float* ex_w2 = (const float*)d_in[6];
  const float* ex_b2 = (const float*)d_in[7];
  const float* Wq    = (const float*)d_in[8];
  const float* Wk    = (const float*)d_in[9];
  const float* Wv    = (const float*)d_in[10];
  const float* Wo    = (const float*)d_in[11];
  const float* bo    = (const float*)d_in[12];
  const float* W2d   = (const float*)d_in[13];
  const float* b2d   = (const float*)d_in[14];
  const float* W1    = (const float*)d_in[15];
  const float* b1    = (const float*)d_in[16];
  const float* W2    = (const float*)d_in[17];
  const float* b2    = (const float*)d_in[18];
  const float* g1    = (const float*)d_in[19];
  const float* be1   = (const float*)d_in[20];
  const float* g2    = (const float*)d_in[21];
  const float* be2   = (const float*)d_in[22];
  const float* m3w1  = (const float*)d_in[23];
  const float* m3b1  = (const float*)d_in[24];
  const float* m3w2  = (const float*)d_in[25];
  const float* m3b2  = (const float*)d_in[26];

  float* ws     = (float*)d_ws;
  float* h      = ws;                          // 4096*256
  float* t0     = h + (size_t)ROWS * E;        // 4096*256 (embed hidden / tmp)
  float* r      = t0 + (size_t)ROWS * E;       // 4096*3
  float* bias49 = r + (size_t)ROWS * 3;        // 8*16*49
  unsigned short* us = (unsigned short*)(bias49 + NL * NH * 49);
  unsigned short* hb   = us;                              // 4096*256
  unsigned short* umb  = hb  + (size_t)ROWS * E;          // 4096*288
  unsigned short* qkvb = umb + (size_t)ROWS * (E + E1D);  // 4096*1536
  unsigned short* ob   = qkvb + (size_t)ROWS * 3 * DM;    // 4096*512
  unsigned short* t1b  = ob  + (size_t)ROWS * DM;         // 4096*1024
  unsigned short* qkvT = t1b + (size_t)ROWS * FF;         // 8*1536*256
  unsigned short* WoT  = qkvT + (size_t)NL * 3 * DM * E;  // 8*256*512
  unsigned short* W1T  = WoT  + (size_t)NL * E * DM;      // 8*1024*288
  unsigned short* W2T  = W1T  + (size_t)NL * FF * (E+E1D);// 8*256*1024
  float* tmp = t0;            // layer-loop scratch aliases t0
  float* t1f = (float*)t1b;   // head scratch aliases t1b

  // ---- weight transpose+convert (4 launches) ----
  transpose_qkv<<<dim3(DM/32, E/32, 3*NL), 256, 0, stream>>>(Wq, Wk, Wv, qkvT);
  transpose_bf16<<<dim3(E/32, DM/32, NL), 256, 0, stream>>>(
      Wo, WoT, DM, E, (size_t)DM * E, (size_t)DM * E);
  transpose_bf16<<<dim3(FF/32, (E+E1D)/32, NL), 256, 0, stream>>>(
      W1, W1T, E + E1D, FF, (size_t)(E+E1D) * FF, (size_t)(E+E1D) * FF);
  transpose_bf16<<<dim3(E/32, FF/32, NL), 256, 0, stream>>>(
      W2, W2T, FF, E, (size_t)FF * E, (size_t)FF * E);

  embed1_kernel<<<ROWS, 256, 0, stream>>>(z, x, aa, ex_w1, ex_b1, t0, umb);
  gemm64f<false,true,true><<<dim3(E/64, ROWS/64), 256, 0, stream>>>(
      t0, ex_w2, ex_b2, h, hb, E, E);
  bias_kernel<<<NL, 256, 0, stream>>>(pos, W2d, b2d, bias49);

  for (int i = 0; i < NL; ++i) {
    // fused QKV: N=1536, 64x128 tiles -> 768 blocks (3/CU)
    gemm_mfma<64,128,false,false,true,true><<<dim3(12, 64), 256, 0, stream>>>(
        hb, qkvT + (size_t)i * 3 * DM * E, nullptr, nullptr, qkvb, 3 * DM, E);
    attn_kernel<<<dim3(Ln/64, Bn*NH), 256, 0, stream>>>(
        qkvb, bias49 + (size_t)i * NH * 49, ob);
    // Wo + bias + resid(h) -> tmp fp32  (1024 blocks, 4/CU — R8 proven)
    gemm_n256<<<dim3(E/32, ROWS/32), 256, 0, stream>>>(
        ob, WoT + (size_t)i * DM * E, bo + (size_t)i * E, h, tmp, DM);
    ln_kernel<<<ROWS/4, 256, 0, stream>>>(tmp, g1 + (size_t)i * E, be1 + (size_t)i * E, h, umb, E + E1D);
    // FF1 + bias + relu -> bf16 t1b  (64x64 tiles -> 1024 blocks, 4/CU)
    gemm_mfma<64,64,true,true,true,false><<<dim3(FF/64, ROWS/64), 256, 0, stream>>>(
        umb, W1T + (size_t)i * FF * (E+E1D), b1 + (size_t)i * FF, nullptr, t1b, FF, E + E1D);
    // FF2 + bias + resid(h) -> tmp fp32  (1024 blocks, 4/CU — R8 proven)
    gemm_n256<<<dim3(E/32, ROWS/32), 256, 0, stream>>>(
        t1b, W2T + (size_t)i * E * FF, b2 + (size_t)i * E, h, tmp, FF);
    ln_kernel<<<ROWS/4, 256, 0, stream>>>(tmp, g2 + (size_t)i * E, be2 + (size_t)i * E, h, hb, E);
  }

  // fp32 head
  gemm64f<true,true,false><<<dim3(E/64, ROWS/64), 256, 0, stream>>>(
      h, m3w1, m3b1, t1f, nullptr, E, E);
  final_r_kernel<<<ROWS, 256, 0, stream>>>(t1f, m3w2, m3b2, r);
  dist_kernel<<<ROWS, 512, 0, stream>>>(r, (float*)d_out);
}